// Round 2
// baseline (212.482 us; speedup 1.0000x reference)
//
#include <hip/hip_runtime.h>
#include <math.h>

#define HS 8
#define E 12
#define NA 20
#define KC 4

// Precomputed, batch-independent tables (filled by precompute_kernel):
__device__ float g_Wt[128 * 32];      // (sc_w1[:, :128] @ ctx_w2)^T  : [m][j]
__device__ float g_abias[NA * 32];    // per-action score-layer bias
__device__ float g_QKVT[54 * 48];     // per-card qkv: [card][head*12 + slot(0..8), pad 9..11]
__device__ float g_ENCTX[54 * 128];   // enemy contribution to ctx1 pre-act: [card][m]
__device__ float g_ctxw1r[128 * 24];  // ctx_w1 cols {0..11, 24..35} packed: [m][24]
__device__ float g_dpw1p[64 * 56];    // dp_w1 padded rows: [row][56]
__device__ float g_gsw2T[64 * 8];     // gs_w2 transposed+padded: [row][8]
__device__ float g_dpw2T[64 * 8];     // dp_w2 transposed+padded: [row][8]

__global__ void precompute_kernel(const float* __restrict__ card_emb,
                                  const int* __restrict__ aci,
                                  const float* __restrict__ ctx_w2,
                                  const float* __restrict__ ctx_b2,
                                  const float* __restrict__ sc_w1,
                                  const float* __restrict__ sc_b1,
                                  const float* __restrict__ in_w,
                                  const float* __restrict__ in_b,
                                  const float* __restrict__ enemy_emb,
                                  const float* __restrict__ ctx_w1,
                                  const float* __restrict__ gs_w2,
                                  const float* __restrict__ dp_w2,
                                  const float* __restrict__ dp_w1) {
    int t = blockIdx.x * blockDim.x + threadIdx.x;
    const int OA = 4096, OB = OA + NA * 32, OC = OB + 54 * 48, OD = OC + 54 * 128;
    const int OE = OD + 128 * 24, OF = OE + 64 * 56, OG = OF + 64 * 8, OH = OG + 64 * 8;
    if (t < OA) {
        int m = t >> 5, j = t & 31;
        float s = 0.f;
        for (int i = 0; i < 128; ++i) s += sc_w1[j * 140 + i] * ctx_w2[i * 128 + m];
        g_Wt[t] = s;
    } else if (t < OB) {
        int t2 = t - OA;
        int a = t2 >> 5, j = t2 & 31;
        float arep[E];
#pragma unroll
        for (int k2 = 0; k2 < E; ++k2) arep[k2] = 0.f;
        float cnt = 0.f;
#pragma unroll
        for (int c = 0; c < KC; ++c) {
            int idx = aci[a * KC + c];
            if (idx != 0) {
                cnt += 1.f;
#pragma unroll
                for (int k2 = 0; k2 < E; ++k2) arep[k2] += card_emb[idx * E + k2];
            }
        }
        float inv = 1.f / fmaxf(cnt, 1.f);
        float s = sc_b1[j];
#pragma unroll
        for (int k2 = 0; k2 < E; ++k2) s += sc_w1[j * 140 + 128 + k2] * (arep[k2] * inv);
        for (int i = 0; i < 128; ++i) s += sc_w1[j * 140 + i] * ctx_b2[i];
        g_abias[t2] = s;
    } else if (t < OC) {
        int t2 = t - OB;
        int c = t2 / 48, col = t2 % 48;
        int h = col / 12, s = col % 12;
        float val = 0.f;
        if (s < 9) {
            int r;
            if (s < 3) r = h * 3 + s;
            else if (s < 6) r = 12 + h * 3 + (s - 3);
            else r = 24 + h * 3 + (s - 6);
            val = in_b[r];
#pragma unroll
            for (int j = 0; j < 12; ++j) val += in_w[r * 12 + j] * card_emb[c * 12 + j];
        }
        g_QKVT[t2] = val;
    } else if (t < OD) {
        int t2 = t - OC;
        int c = t2 >> 7, m = t2 & 127;
        float s = 0.f;
#pragma unroll
        for (int i = 0; i < 12; ++i) s += ctx_w1[m * 36 + 12 + i] * enemy_emb[c * 12 + i];
        g_ENCTX[t2] = s;
    } else if (t < OE) {
        int t2 = t - OD;
        int m = t2 / 24, i = t2 % 24;
        int col = (i < 12) ? i : (i + 12);
        g_ctxw1r[t2] = ctx_w1[m * 36 + col];
    } else if (t < OF) {
        int t2 = t - OE;
        int r = t2 / 56, cc = t2 % 56;
        g_dpw1p[t2] = (cc < 54) ? dp_w1[r * 54 + cc] : 0.f;
    } else if (t < OG) {
        int t2 = t - OF;
        int jj = t2 / 8, c = t2 % 8;
        g_gsw2T[t2] = (c < 6) ? gs_w2[c * 64 + jj] : 0.f;
    } else if (t < OH) {
        int t2 = t - OG;
        int jj = t2 / 8, c = t2 % 8;
        g_dpw2T[t2] = (c < 6) ? dp_w2[c * 64 + jj] : 0.f;
    }
}

// 4 lanes per batch element: q = tid&3. Block 512 = 128 elements, 8 waves.
__global__ __launch_bounds__(512, 4) void policy_kernel(
    const int* __restrict__ hand_cards, const float* __restrict__ game_state,
    const float* __restrict__ discard, const int* __restrict__ enemy_card,
    const int* __restrict__ hand_size, const int* __restrict__ num_valid,
    const float* __restrict__ out_w, const float* __restrict__ out_b,
    const float* __restrict__ gs_w1, const float* __restrict__ gs_b1,
    const float* __restrict__ gs_b2, const float* __restrict__ dp_b1,
    const float* __restrict__ dp_b2, const float* __restrict__ ctx_b1,
    const float* __restrict__ sc_w2, const float* __restrict__ sc_b2,
    float* __restrict__ out, int Btot) {
    __shared__ __align__(16) float sQKVT[54 * 48];
    __shared__ __align__(16) float sGS1[64 * 12];
    __shared__ __align__(16) float sGS2[64 * 8];
    __shared__ __align__(16) float sDP1[64 * 56];
    __shared__ __align__(16) float sDP2[64 * 8];
    __shared__ __align__(16) float sCTX[128 * 24];
    __shared__ __align__(16) float sAB[NA * 32];
    __shared__ __align__(16) float sOW[12 * 12];
    __shared__ __align__(16) float sW2[32];
    __shared__ __align__(16) float sGSB1[64];
    __shared__ __align__(16) float sDPB1[64];
    __shared__ __align__(16) float sCTXB1[128];

    int tid = threadIdx.x;
    for (int i = tid; i < 54 * 48; i += 512) sQKVT[i] = g_QKVT[i];
    for (int i = tid; i < 64 * 12; i += 512) sGS1[i] = gs_w1[i];
    for (int i = tid; i < 64 * 8; i += 512) sGS2[i] = g_gsw2T[i];
    for (int i = tid; i < 64 * 56; i += 512) sDP1[i] = g_dpw1p[i];
    for (int i = tid; i < 64 * 8; i += 512) sDP2[i] = g_dpw2T[i];
    for (int i = tid; i < 128 * 24; i += 512) sCTX[i] = g_ctxw1r[i];
    for (int i = tid; i < NA * 32; i += 512) sAB[i] = g_abias[i];
    if (tid < 144) sOW[tid] = out_w[tid];
    if (tid >= 256 && tid < 288) sW2[tid - 256] = sc_w2[tid - 256];
    if (tid >= 288 && tid < 352) sGSB1[tid - 288] = gs_b1[tid - 288];
    if (tid >= 352 && tid < 416) sDPB1[tid - 352] = dp_b1[tid - 352];
    if (tid < 256 && tid >= 128) sCTXB1[tid - 128] = ctx_b1[tid - 128];
    __syncthreads();

    int q = tid & 3;
    int b = blockIdx.x * 128 + (tid >> 2);
    if (b >= Btot) return;
    int lane = tid & 63;
    int base = lane & ~3;

    // ---- per-element inputs ----
    int hc[HS];
    {
        const int4* hp = (const int4*)(hand_cards + (size_t)b * HS);
        int4 h0 = hp[0], h1 = hp[1];
        hc[0] = h0.x; hc[1] = h0.y; hc[2] = h0.z; hc[3] = h0.w;
        hc[4] = h1.x; hc[5] = h1.y; hc[6] = h1.z; hc[7] = h1.w;
    }
    int ec = enemy_card[b];

    // ---- attention: lane q owns head q ----
    float qk[HS][9];
#pragma unroll
    for (int p = 0; p < HS; ++p) {
        const float4* tp = (const float4*)&sQKVT[hc[p] * 48 + q * 12];
        float4 a0 = tp[0], a1 = tp[1], a2 = tp[2];
        qk[p][0] = a0.x; qk[p][1] = a0.y; qk[p][2] = a0.z;
        qk[p][3] = a0.w; qk[p][4] = a1.x; qk[p][5] = a1.y;
        qk[p][6] = a1.z; qk[p][7] = a1.w; qk[p][8] = a2.x;
    }
    const float scale = 0.5773502691896258f;
    float attv0 = 0.f, attv1 = 0.f, attv2 = 0.f;
#pragma unroll
    for (int p = 0; p < HS; ++p) {
        float s[HS];
        float mx = -3.0e38f;
#pragma unroll
        for (int k = 0; k < HS; ++k) {
            float t = (qk[p][0] * qk[k][3] + qk[p][1] * qk[k][4] + qk[p][2] * qk[k][5]) * scale;
            t = (hc[k] != 0) ? t : -1.0e9f;
            s[k] = t;
            mx = fmaxf(mx, t);
        }
        float sum = 0.f;
#pragma unroll
        for (int k = 0; k < HS; ++k) {
            float e = __expf(s[k] - mx);
            s[k] = e;
            sum += e;
        }
        float inv = 1.f / sum;
        float a0 = 0.f, a1 = 0.f, a2 = 0.f;
#pragma unroll
        for (int k = 0; k < HS; ++k) {
            a0 += s[k] * qk[k][6];
            a1 += s[k] * qk[k][7];
            a2 += s[k] * qk[k][8];
        }
        attv0 += a0 * inv; attv1 += a1 * inv; attv2 += a2 * inv;
    }
    // all-gather attsum[12] (lane j/3 owns component j%3)
    float attw[12];
#pragma unroll
    for (int j = 0; j < 12; ++j) {
        float v = (j % 3 == 0) ? attv0 : ((j % 3 == 1) ? attv1 : attv2);
        attw[j] = __shfl(v, base + j / 3, 64);
    }
    // out_w rows 3q..3q+2
    float ho[3];
    {
        float invlen = 1.f / fmaxf((float)hand_size[b], 1.f);
#pragma unroll
        for (int t2 = 0; t2 < 3; ++t2) {
            int r = 3 * q + t2;
            float a = 8.f * out_b[r];
#pragma unroll
            for (int e = 0; e < 12; ++e) a += sOW[r * 12 + e] * attw[e];
            ho[t2] = a * invlen;
        }
    }

    // ---- game_state MLP: rows 16q..16q+15 ----
    float g6[6];
    {
        const float4* gp = (const float4*)(game_state + (size_t)b * 12);
        float4 x0 = gp[0], x1 = gp[1], x2 = gp[2];
        float acc[6] = {0.f, 0.f, 0.f, 0.f, 0.f, 0.f};
#pragma unroll 4
        for (int jj = 0; jj < 16; ++jj) {
            int row = q * 16 + jj;
            const float4* wr = (const float4*)&sGS1[row * 12];
            float4 w0 = wr[0], w1 = wr[1], w2 = wr[2];
            float h = sGSB1[row];
            h += w0.x * x0.x + w0.y * x0.y + w0.z * x0.z + w0.w * x0.w;
            h += w1.x * x1.x + w1.y * x1.y + w1.z * x1.z + w1.w * x1.w;
            h += w2.x * x2.x + w2.y * x2.y + w2.z * x2.z + w2.w * x2.w;
            h = fmaxf(h, 0.f);
            const float4* w2r = (const float4*)&sGS2[row * 8];
            float4 wa = w2r[0], wb = w2r[1];
            acc[0] += h * wa.x; acc[1] += h * wa.y; acc[2] += h * wa.z;
            acc[3] += h * wa.w; acc[4] += h * wb.x; acc[5] += h * wb.y;
        }
#pragma unroll
        for (int c = 0; c < 6; ++c) {
            float v = acc[c];
            v += __shfl_xor(v, 1, 64);
            v += __shfl_xor(v, 2, 64);
            g6[c] = v + gs_b2[c];
        }
    }
    // ---- discard MLP: rows 16q..16q+15 ----
    float d6[6];
    {
        float x[56];
        const float2* dp2 = (const float2*)(discard + (size_t)b * 54);
#pragma unroll
        for (int i = 0; i < 27; ++i) {
            float2 t = dp2[i];
            x[2 * i] = t.x;
            x[2 * i + 1] = t.y;
        }
        x[54] = 0.f; x[55] = 0.f;
        float acc[6] = {0.f, 0.f, 0.f, 0.f, 0.f, 0.f};
#pragma unroll 4
        for (int jj = 0; jj < 16; ++jj) {
            int row = q * 16 + jj;
            const float4* wr = (const float4*)&sDP1[row * 56];
            float h = sDPB1[row];
#pragma unroll
            for (int i = 0; i < 14; ++i) {
                float4 w = wr[i];
                h += w.x * x[4 * i] + w.y * x[4 * i + 1] + w.z * x[4 * i + 2] + w.w * x[4 * i + 3];
            }
            h = fmaxf(h, 0.f);
            const float4* w2r = (const float4*)&sDP2[row * 8];
            float4 wa = w2r[0], wb = w2r[1];
            acc[0] += h * wa.x; acc[1] += h * wa.y; acc[2] += h * wa.z;
            acc[3] += h * wa.w; acc[4] += h * wb.x; acc[5] += h * wb.y;
        }
#pragma unroll
        for (int c = 0; c < 6; ++c) {
            float v = acc[c];
            v += __shfl_xor(v, 1, 64);
            v += __shfl_xor(v, 2, 64);
            d6[c] = v + dp_b2[c];
        }
    }

    // ---- ctx1 (rows 32q..32q+31) fused with folded u-projection ----
    float cv[24];
#pragma unroll
    for (int i = 0; i < 12; ++i) cv[i] = __shfl(ho[i % 3], base + i / 3, 64);
#pragma unroll
    for (int c = 0; c < 6; ++c) { cv[12 + c] = g6[c]; cv[18 + c] = d6[c]; }

    float u[32];
#pragma unroll
    for (int j = 0; j < 32; ++j) u[j] = 0.f;
    const float4* encp = (const float4*)(g_ENCTX + ec * 128 + q * 32);
    const float* gwbase = g_Wt + q * 32 * 32;
#pragma unroll 2
    for (int mt = 0; mt < 8; ++mt) {
        float4 e4 = encp[mt];
        float eb[4] = {e4.x, e4.y, e4.z, e4.w};
#pragma unroll
        for (int t2 = 0; t2 < 4; ++t2) {
            int mm = mt * 4 + t2;
            int m = q * 32 + mm;
            const float4* wr = (const float4*)&sCTX[m * 24];
            float h = sCTXB1[m] + eb[t2];
            float4 w0 = wr[0], w1 = wr[1], w2 = wr[2], w3 = wr[3], w4 = wr[4], w5 = wr[5];
            h += w0.x * cv[0] + w0.y * cv[1] + w0.z * cv[2] + w0.w * cv[3];
            h += w1.x * cv[4] + w1.y * cv[5] + w1.z * cv[6] + w1.w * cv[7];
            h += w2.x * cv[8] + w2.y * cv[9] + w2.z * cv[10] + w2.w * cv[11];
            h += w3.x * cv[12] + w3.y * cv[13] + w3.z * cv[14] + w3.w * cv[15];
            h += w4.x * cv[16] + w4.y * cv[17] + w4.z * cv[18] + w4.w * cv[19];
            h += w5.x * cv[20] + w5.y * cv[21] + w5.z * cv[22] + w5.w * cv[23];
            h = fmaxf(h, 0.f);
            const float4* gw = (const float4*)(gwbase + mm * 32);
#pragma unroll
            for (int j8 = 0; j8 < 8; ++j8) {
                float4 w = gw[j8];
                u[4 * j8 + 0] += h * w.x;
                u[4 * j8 + 1] += h * w.y;
                u[4 * j8 + 2] += h * w.z;
                u[4 * j8 + 3] += h * w.w;
            }
        }
    }
    // reduce u across 4 lanes (all lanes get total)
#pragma unroll
    for (int j = 0; j < 32; ++j) {
        float v = u[j];
        v += __shfl_xor(v, 1, 64);
        v += __shfl_xor(v, 2, 64);
        u[j] = v;
    }

    // ---- actions 5q..5q+4 ----
    float w2r[32];
#pragma unroll
    for (int j8 = 0; j8 < 8; ++j8) {
        float4 w = ((const float4*)sW2)[j8];
        w2r[4 * j8 + 0] = w.x; w2r[4 * j8 + 1] = w.y;
        w2r[4 * j8 + 2] = w.z; w2r[4 * j8 + 3] = w.w;
    }
    int nva = num_valid[0];
    float sb2 = sc_b2[0];
#pragma unroll
    for (int t2 = 0; t2 < 5; ++t2) {
        int a = q * 5 + t2;
        const float4* ab = (const float4*)&sAB[a * 32];
        float s = sb2;
#pragma unroll
        for (int j8 = 0; j8 < 8; ++j8) {
            float4 av = ab[j8];
            s += w2r[4 * j8 + 0] * fmaxf(u[4 * j8 + 0] + av.x, 0.f);
            s += w2r[4 * j8 + 1] * fmaxf(u[4 * j8 + 1] + av.y, 0.f);
            s += w2r[4 * j8 + 2] * fmaxf(u[4 * j8 + 2] + av.z, 0.f);
            s += w2r[4 * j8 + 3] * fmaxf(u[4 * j8 + 3] + av.w, 0.f);
        }
        out[(size_t)b * NA + a] = (a < nva) ? s : -1.0e8f;
    }
}

extern "C" void kernel_launch(void* const* d_in, const int* in_sizes, int n_in,
                              void* d_out, int out_size, void* d_ws, size_t ws_size,
                              hipStream_t stream) {
    const int* hand_cards = (const int*)d_in[0];
    const float* game_state = (const float*)d_in[1];
    const float* discard = (const float*)d_in[2];
    const int* enemy_card = (const int*)d_in[3];
    const int* hand_size = (const int*)d_in[4];
    const int* aci = (const int*)d_in[5];
    const int* num_valid = (const int*)d_in[6];
    const float* card_emb = (const float*)d_in[7];
    const float* enemy_emb = (const float*)d_in[8];
    const float* in_w = (const float*)d_in[9];
    const float* in_b = (const float*)d_in[10];
    const float* out_w = (const float*)d_in[11];
    const float* out_b = (const float*)d_in[12];
    const float* gs_w1 = (const float*)d_in[13];
    const float* gs_b1 = (const float*)d_in[14];
    const float* gs_w2 = (const float*)d_in[15];
    const float* gs_b2 = (const float*)d_in[16];
    const float* dp_w1 = (const float*)d_in[17];
    const float* dp_b1 = (const float*)d_in[18];
    const float* dp_w2 = (const float*)d_in[19];
    const float* dp_b2 = (const float*)d_in[20];
    const float* ctx_w1 = (const float*)d_in[21];
    const float* ctx_b1 = (const float*)d_in[22];
    const float* ctx_w2 = (const float*)d_in[23];
    const float* ctx_b2 = (const float*)d_in[24];
    const float* sc_w1 = (const float*)d_in[25];
    const float* sc_b1 = (const float*)d_in[26];
    const float* sc_w2 = (const float*)d_in[27];
    const float* sc_b2 = (const float*)d_in[28];

    int B = in_sizes[0] / HS;

    precompute_kernel<<<86, 256, 0, stream>>>(card_emb, aci, ctx_w2, ctx_b2, sc_w1, sc_b1,
                                              in_w, in_b, enemy_emb, ctx_w1, gs_w2, dp_w2,
                                              dp_w1);
    policy_kernel<<<(B + 127) / 128, 512, 0, stream>>>(
        hand_cards, game_state, discard, enemy_card, hand_size, num_valid,
        out_w, out_b, gs_w1, gs_b1, gs_b2, dp_b1, dp_b2, ctx_b1, sc_w2, sc_b2,
        (float*)d_out, B);
}

// Round 3
// 77.714 us; speedup vs baseline: 2.7342x; 2.7342x over previous
//
#include <hip/hip_runtime.h>
#include <math.h>

#define HS 8
#define E 12
#define NA 20
#define KC 4

// Precomputed, batch-independent tables (filled by precompute_kernel):
__device__ float g_Wt[128 * 32];      // (sc_w1[:, :128] @ ctx_w2)^T  : [m][j]
__device__ float g_abias[NA * 32];    // per-action score-layer bias
__device__ float g_QKVT[54 * 48];     // per-card qkv: [card][head*12 + slot(0..8), pad]
__device__ float g_ENCTX[54 * 128];   // enemy contribution to ctx1 pre-act: [card][m]
__device__ float g_ctxw1r[128 * 24];  // ctx_w1 cols {0..11, 24..35} packed: [m][24]
__device__ float g_dpw1p[64 * 56];    // dp_w1 padded rows: [row][56]
__device__ float g_gsw2T[64 * 8];     // gs_w2 transposed+padded: [row][8]
__device__ float g_dpw2T[64 * 8];     // dp_w2 transposed+padded: [row][8]

__global__ void precompute_kernel(const float* __restrict__ card_emb,
                                  const int* __restrict__ aci,
                                  const float* __restrict__ ctx_w2,
                                  const float* __restrict__ ctx_b2,
                                  const float* __restrict__ sc_w1,
                                  const float* __restrict__ sc_b1,
                                  const float* __restrict__ in_w,
                                  const float* __restrict__ in_b,
                                  const float* __restrict__ enemy_emb,
                                  const float* __restrict__ ctx_w1,
                                  const float* __restrict__ gs_w2,
                                  const float* __restrict__ dp_w2,
                                  const float* __restrict__ dp_w1) {
    int t = blockIdx.x * blockDim.x + threadIdx.x;
    const int OA = 4096, OB = OA + NA * 32, OC = OB + 54 * 48, OD = OC + 54 * 128;
    const int OE = OD + 128 * 24, OF = OE + 64 * 56, OG = OF + 64 * 8, OH = OG + 64 * 8;
    if (t < OA) {
        int m = t >> 5, j = t & 31;
        float s = 0.f;
        for (int i = 0; i < 128; ++i) s += sc_w1[j * 140 + i] * ctx_w2[i * 128 + m];
        g_Wt[t] = s;
    } else if (t < OB) {
        int t2 = t - OA;
        int a = t2 >> 5, j = t2 & 31;
        float arep[E];
#pragma unroll
        for (int k2 = 0; k2 < E; ++k2) arep[k2] = 0.f;
        float cnt = 0.f;
#pragma unroll
        for (int c = 0; c < KC; ++c) {
            int idx = aci[a * KC + c];
            if (idx != 0) {
                cnt += 1.f;
#pragma unroll
                for (int k2 = 0; k2 < E; ++k2) arep[k2] += card_emb[idx * E + k2];
            }
        }
        float inv = 1.f / fmaxf(cnt, 1.f);
        float s = sc_b1[j];
#pragma unroll
        for (int k2 = 0; k2 < E; ++k2) s += sc_w1[j * 140 + 128 + k2] * (arep[k2] * inv);
        for (int i = 0; i < 128; ++i) s += sc_w1[j * 140 + i] * ctx_b2[i];
        g_abias[t2] = s;
    } else if (t < OC) {
        int t2 = t - OB;
        int c = t2 / 48, col = t2 % 48;
        int h = col / 12, s = col % 12;
        float val = 0.f;
        if (s < 9) {
            int r;
            if (s < 3) r = h * 3 + s;
            else if (s < 6) r = 12 + h * 3 + (s - 3);
            else r = 24 + h * 3 + (s - 6);
            val = in_b[r];
#pragma unroll
            for (int j = 0; j < 12; ++j) val += in_w[r * 12 + j] * card_emb[c * 12 + j];
        }
        g_QKVT[t2] = val;
    } else if (t < OD) {
        int t2 = t - OC;
        int c = t2 >> 7, m = t2 & 127;
        float s = 0.f;
#pragma unroll
        for (int i = 0; i < 12; ++i) s += ctx_w1[m * 36 + 12 + i] * enemy_emb[c * 12 + i];
        g_ENCTX[t2] = s;
    } else if (t < OE) {
        int t2 = t - OD;
        int m = t2 / 24, i = t2 % 24;
        int col = (i < 12) ? i : (i + 12);
        g_ctxw1r[t2] = ctx_w1[m * 36 + col];
    } else if (t < OF) {
        int t2 = t - OE;
        int r = t2 / 56, cc = t2 % 56;
        g_dpw1p[t2] = (cc < 54) ? dp_w1[r * 54 + cc] : 0.f;
    } else if (t < OG) {
        int t2 = t - OF;
        int jj = t2 / 8, c = t2 % 8;
        g_gsw2T[t2] = (c < 6) ? gs_w2[c * 64 + jj] : 0.f;
    } else if (t < OH) {
        int t2 = t - OG;
        int jj = t2 / 8, c = t2 % 8;
        g_dpw2T[t2] = (c < 6) ? dp_w2[c * 64 + jj] : 0.f;
    }
}

// 4 lanes per batch element: q = tid&3. Block 512 = 128 elements, 8 waves.
// LDS tables re-indexed so the 4 lanes of a quad hit distinct banks:
//   row-split tables use [jj][q][stride] interleave (stride not 0 mod 32 banks).
__global__ __launch_bounds__(512) void policy_kernel(
    const int* __restrict__ hand_cards, const float* __restrict__ game_state,
    const float* __restrict__ discard, const int* __restrict__ enemy_card,
    const int* __restrict__ hand_size, const int* __restrict__ num_valid,
    const float* __restrict__ out_w, const float* __restrict__ out_b,
    const float* __restrict__ gs_w1, const float* __restrict__ gs_b1,
    const float* __restrict__ gs_b2, const float* __restrict__ dp_b1,
    const float* __restrict__ dp_b2, const float* __restrict__ ctx_b1,
    const float* __restrict__ sc_w2, const float* __restrict__ sc_b2,
    float* __restrict__ out, int Btot) {
    __shared__ __align__(16) float sQKVT[54 * 48];
    __shared__ __align__(16) float sGS1[64 * 12];   // [(jj*4+q)*12]
    __shared__ __align__(16) float sGS2[64 * 8];    // [(jj*4+q)*8]
    __shared__ __align__(16) float sDP1[64 * 56];   // [(jj*4+q)*56]
    __shared__ __align__(16) float sDP2[64 * 8];    // [(jj*4+q)*8]
    __shared__ __align__(16) float sCTX[128 * 28];  // [(mm*4+q)*28]
    __shared__ __align__(16) float sWT[128 * 36];   // [(mm*4+q)*36]
    __shared__ __align__(16) float sAB[NA * 36];    // stride 36
    __shared__ __align__(16) float sOW[12 * 12];
    __shared__ __align__(16) float sW2[32];
    __shared__ __align__(16) float sGSB1[64];
    __shared__ __align__(16) float sDPB1[64];
    __shared__ __align__(16) float sCTXB1[128];     // [(mm*4+q)]

    int tid = threadIdx.x;
    for (int i = tid; i < 54 * 48; i += 512) sQKVT[i] = g_QKVT[i];
    for (int i = tid; i < 64 * 12; i += 512) {
        int r = i / 12, c = i % 12;
        sGS1[((r & 15) * 4 + (r >> 4)) * 12 + c] = gs_w1[i];
    }
    for (int i = tid; i < 64 * 8; i += 512) {
        int r = i >> 3, c = i & 7;
        int s = ((r & 15) * 4 + (r >> 4)) * 8 + c;
        sGS2[s] = g_gsw2T[i];
        sDP2[s] = g_dpw2T[i];
    }
    for (int i = tid; i < 64 * 56; i += 512) {
        int r = i / 56, c = i % 56;
        sDP1[((r & 15) * 4 + (r >> 4)) * 56 + c] = g_dpw1p[i];
    }
    for (int i = tid; i < 128 * 28; i += 512) {
        int s = i / 28, c = i % 28;
        int m = (s & 3) * 32 + (s >> 2);
        sCTX[i] = (c < 24) ? g_ctxw1r[m * 24 + c] : 0.f;
    }
    for (int i = tid; i < 128 * 36; i += 512) {
        int s = i / 36, c = i % 36;
        int m = (s & 3) * 32 + (s >> 2);
        sWT[i] = (c < 32) ? g_Wt[m * 32 + c] : 0.f;
    }
    for (int i = tid; i < NA * 36; i += 512) {
        int a = i / 36, c = i % 36;
        sAB[i] = (c < 32) ? g_abias[a * 32 + c] : 0.f;
    }
    if (tid < 144) sOW[tid] = out_w[tid];
    if (tid >= 160 && tid < 192) sW2[tid - 160] = sc_w2[tid - 160];
    if (tid >= 192 && tid < 256) sGSB1[tid - 192] = gs_b1[tid - 192];
    if (tid >= 256 && tid < 320) sDPB1[tid - 256] = dp_b1[tid - 256];
    if (tid >= 320 && tid < 448) {
        int m = tid - 320;
        sCTXB1[(m & 31) * 4 + (m >> 5)] = ctx_b1[m];
    }
    __syncthreads();

    int q = tid & 3;
    int b = blockIdx.x * 128 + (tid >> 2);
    if (b >= Btot) return;
    int lane = tid & 63;
    int base = lane & ~3;

    // ---- per-element inputs ----
    int hc[HS];
    {
        const int4* hp = (const int4*)(hand_cards + (size_t)b * HS);
        int4 h0 = hp[0], h1 = hp[1];
        hc[0] = h0.x; hc[1] = h0.y; hc[2] = h0.z; hc[3] = h0.w;
        hc[4] = h1.x; hc[5] = h1.y; hc[6] = h1.z; hc[7] = h1.w;
    }
    int ec = enemy_card[b];

    // ---- attention: lane q owns head q ----
    float qk[HS][9];
#pragma unroll
    for (int p = 0; p < HS; ++p) {
        const float4* tp = (const float4*)&sQKVT[hc[p] * 48 + q * 12];
        float4 a0 = tp[0], a1 = tp[1], a2 = tp[2];
        qk[p][0] = a0.x; qk[p][1] = a0.y; qk[p][2] = a0.z;
        qk[p][3] = a0.w; qk[p][4] = a1.x; qk[p][5] = a1.y;
        qk[p][6] = a1.z; qk[p][7] = a1.w; qk[p][8] = a2.x;
    }
    const float scale = 0.5773502691896258f;
    float attv0 = 0.f, attv1 = 0.f, attv2 = 0.f;
#pragma unroll
    for (int p = 0; p < HS; ++p) {
        float s[HS];
        float mx = -3.0e38f;
#pragma unroll
        for (int k = 0; k < HS; ++k) {
            float t = (qk[p][0] * qk[k][3] + qk[p][1] * qk[k][4] + qk[p][2] * qk[k][5]) * scale;
            t = (hc[k] != 0) ? t : -1.0e9f;
            s[k] = t;
            mx = fmaxf(mx, t);
        }
        float sum = 0.f;
#pragma unroll
        for (int k = 0; k < HS; ++k) {
            float e = __expf(s[k] - mx);
            s[k] = e;
            sum += e;
        }
        float inv = 1.f / sum;
        float a0 = 0.f, a1 = 0.f, a2 = 0.f;
#pragma unroll
        for (int k = 0; k < HS; ++k) {
            a0 += s[k] * qk[k][6];
            a1 += s[k] * qk[k][7];
            a2 += s[k] * qk[k][8];
        }
        attv0 += a0 * inv; attv1 += a1 * inv; attv2 += a2 * inv;
    }
    // all-gather attsum[12] (lane j/3 of quad owns component j%3)
    float attw[12];
#pragma unroll
    for (int j = 0; j < 12; ++j) {
        float v = (j % 3 == 0) ? attv0 : ((j % 3 == 1) ? attv1 : attv2);
        attw[j] = __shfl(v, base + j / 3, 64);
    }
    // out_w rows 3q..3q+2
    float ho[3];
    {
        float invlen = 1.f / fmaxf((float)hand_size[b], 1.f);
#pragma unroll
        for (int t2 = 0; t2 < 3; ++t2) {
            int r = 3 * q + t2;
            float a = 8.f * out_b[r];
#pragma unroll
            for (int e = 0; e < 12; ++e) a += sOW[r * 12 + e] * attw[e];
            ho[t2] = a * invlen;
        }
    }

    // ---- game_state MLP: rows q*16..q*16+15 ----
    float g6[6];
    {
        const float4* gp = (const float4*)(game_state + (size_t)b * 12);
        float4 x0 = gp[0], x1 = gp[1], x2 = gp[2];
        float acc[6] = {0.f, 0.f, 0.f, 0.f, 0.f, 0.f};
#pragma unroll 4
        for (int jj = 0; jj < 16; ++jj) {
            const float4* wr = (const float4*)&sGS1[(jj * 4 + q) * 12];
            float4 w0 = wr[0], w1 = wr[1], w2 = wr[2];
            float h = sGSB1[q * 16 + jj];
            h += w0.x * x0.x + w0.y * x0.y + w0.z * x0.z + w0.w * x0.w;
            h += w1.x * x1.x + w1.y * x1.y + w1.z * x1.z + w1.w * x1.w;
            h += w2.x * x2.x + w2.y * x2.y + w2.z * x2.z + w2.w * x2.w;
            h = fmaxf(h, 0.f);
            const float4* w2r = (const float4*)&sGS2[(jj * 4 + q) * 8];
            float4 wa = w2r[0], wb = w2r[1];
            acc[0] += h * wa.x; acc[1] += h * wa.y; acc[2] += h * wa.z;
            acc[3] += h * wa.w; acc[4] += h * wb.x; acc[5] += h * wb.y;
        }
#pragma unroll
        for (int c = 0; c < 6; ++c) {
            float v = acc[c];
            v += __shfl_xor(v, 1, 64);
            v += __shfl_xor(v, 2, 64);
            g6[c] = v + gs_b2[c];
        }
    }
    // ---- discard MLP: rows q*16..q*16+15 ----
    float d6[6];
    {
        float x[56];
        const float2* dp2 = (const float2*)(discard + (size_t)b * 54);
#pragma unroll
        for (int i = 0; i < 27; ++i) {
            float2 t = dp2[i];
            x[2 * i] = t.x;
            x[2 * i + 1] = t.y;
        }
        x[54] = 0.f; x[55] = 0.f;
        float acc[6] = {0.f, 0.f, 0.f, 0.f, 0.f, 0.f};
#pragma unroll 2
        for (int jj = 0; jj < 16; ++jj) {
            const float4* wr = (const float4*)&sDP1[(jj * 4 + q) * 56];
            float h = sDPB1[q * 16 + jj];
#pragma unroll
            for (int i = 0; i < 14; ++i) {
                float4 w = wr[i];
                h += w.x * x[4 * i] + w.y * x[4 * i + 1] + w.z * x[4 * i + 2] + w.w * x[4 * i + 3];
            }
            h = fmaxf(h, 0.f);
            const float4* w2r = (const float4*)&sDP2[(jj * 4 + q) * 8];
            float4 wa = w2r[0], wb = w2r[1];
            acc[0] += h * wa.x; acc[1] += h * wa.y; acc[2] += h * wa.z;
            acc[3] += h * wa.w; acc[4] += h * wb.x; acc[5] += h * wb.y;
        }
#pragma unroll
        for (int c = 0; c < 6; ++c) {
            float v = acc[c];
            v += __shfl_xor(v, 1, 64);
            v += __shfl_xor(v, 2, 64);
            d6[c] = v + dp_b2[c];
        }
    }

    // ---- ctx1 (rows q*32..q*32+31) fused with folded u-projection ----
    float cv[24];
#pragma unroll
    for (int i = 0; i < 12; ++i) cv[i] = __shfl(ho[i % 3], base + i / 3, 64);
#pragma unroll
    for (int c = 0; c < 6; ++c) { cv[12 + c] = g6[c]; cv[18 + c] = d6[c]; }

    float u[32];
#pragma unroll
    for (int j = 0; j < 32; ++j) u[j] = 0.f;
    const float4* encp = (const float4*)(g_ENCTX + ec * 128 + q * 32);
#pragma unroll 2
    for (int mt = 0; mt < 8; ++mt) {
        float4 e4 = encp[mt];
        float eb[4] = {e4.x, e4.y, e4.z, e4.w};
#pragma unroll
        for (int t2 = 0; t2 < 4; ++t2) {
            int mm = mt * 4 + t2;
            const float4* wr = (const float4*)&sCTX[(mm * 4 + q) * 28];
            float h = sCTXB1[mm * 4 + q] + eb[t2];
            float4 w0 = wr[0], w1 = wr[1], w2 = wr[2], w3 = wr[3], w4 = wr[4], w5 = wr[5];
            h += w0.x * cv[0] + w0.y * cv[1] + w0.z * cv[2] + w0.w * cv[3];
            h += w1.x * cv[4] + w1.y * cv[5] + w1.z * cv[6] + w1.w * cv[7];
            h += w2.x * cv[8] + w2.y * cv[9] + w2.z * cv[10] + w2.w * cv[11];
            h += w3.x * cv[12] + w3.y * cv[13] + w3.z * cv[14] + w3.w * cv[15];
            h += w4.x * cv[16] + w4.y * cv[17] + w4.z * cv[18] + w4.w * cv[19];
            h += w5.x * cv[20] + w5.y * cv[21] + w5.z * cv[22] + w5.w * cv[23];
            h = fmaxf(h, 0.f);
            const float4* gw = (const float4*)&sWT[(mm * 4 + q) * 36];
#pragma unroll
            for (int j8 = 0; j8 < 8; ++j8) {
                float4 w = gw[j8];
                u[4 * j8 + 0] += h * w.x;
                u[4 * j8 + 1] += h * w.y;
                u[4 * j8 + 2] += h * w.z;
                u[4 * j8 + 3] += h * w.w;
            }
        }
    }
    // reduce u across the quad (all lanes get total)
#pragma unroll
    for (int j = 0; j < 32; ++j) {
        float v = u[j];
        v += __shfl_xor(v, 1, 64);
        v += __shfl_xor(v, 2, 64);
        u[j] = v;
    }

    // ---- actions q*5..q*5+4 ----
    int nva = num_valid[0];
    float sb2 = sc_b2[0];
#pragma unroll
    for (int t2 = 0; t2 < 5; ++t2) {
        int a = q * 5 + t2;
        const float4* ab = (const float4*)&sAB[a * 36];
        float s = sb2;
#pragma unroll
        for (int j8 = 0; j8 < 8; ++j8) {
            float4 av = ab[j8];
            float4 w = ((const float4*)sW2)[j8];
            s += w.x * fmaxf(u[4 * j8 + 0] + av.x, 0.f);
            s += w.y * fmaxf(u[4 * j8 + 1] + av.y, 0.f);
            s += w.z * fmaxf(u[4 * j8 + 2] + av.z, 0.f);
            s += w.w * fmaxf(u[4 * j8 + 3] + av.w, 0.f);
        }
        out[(size_t)b * NA + a] = (a < nva) ? s : -1.0e8f;
    }
}

extern "C" void kernel_launch(void* const* d_in, const int* in_sizes, int n_in,
                              void* d_out, int out_size, void* d_ws, size_t ws_size,
                              hipStream_t stream) {
    const int* hand_cards = (const int*)d_in[0];
    const float* game_state = (const float*)d_in[1];
    const float* discard = (const float*)d_in[2];
    const int* enemy_card = (const int*)d_in[3];
    const int* hand_size = (const int*)d_in[4];
    const int* aci = (const int*)d_in[5];
    const int* num_valid = (const int*)d_in[6];
    const float* card_emb = (const float*)d_in[7];
    const float* enemy_emb = (const float*)d_in[8];
    const float* in_w = (const float*)d_in[9];
    const float* in_b = (const float*)d_in[10];
    const float* out_w = (const float*)d_in[11];
    const float* out_b = (const float*)d_in[12];
    const float* gs_w1 = (const float*)d_in[13];
    const float* gs_b1 = (const float*)d_in[14];
    const float* gs_w2 = (const float*)d_in[15];
    const float* gs_b2 = (const float*)d_in[16];
    const float* dp_w1 = (const float*)d_in[17];
    const float* dp_b1 = (const float*)d_in[18];
    const float* dp_w2 = (const float*)d_in[19];
    const float* dp_b2 = (const float*)d_in[20];
    const float* ctx_w1 = (const float*)d_in[21];
    const float* ctx_b1 = (const float*)d_in[22];
    const float* ctx_w2 = (const float*)d_in[23];
    const float* ctx_b2 = (const float*)d_in[24];
    const float* sc_w1 = (const float*)d_in[25];
    const float* sc_b1 = (const float*)d_in[26];
    const float* sc_w2 = (const float*)d_in[27];
    const float* sc_b2 = (const float*)d_in[28];

    int B = in_sizes[0] / HS;

    precompute_kernel<<<86, 256, 0, stream>>>(card_emb, aci, ctx_w2, ctx_b2, sc_w1, sc_b1,
                                              in_w, in_b, enemy_emb, ctx_w1, gs_w2, dp_w2,
                                              dp_w1);
    policy_kernel<<<(B + 127) / 128, 512, 0, stream>>>(
        hand_cards, game_state, discard, enemy_card, hand_size, num_valid,
        out_w, out_b, gs_w1, gs_b1, gs_b2, dp_b1, dp_b2, ctx_b1, sc_w2, sc_b2,
        (float*)d_out, B);
}

// Round 4
// 55.749 us; speedup vs baseline: 3.8114x; 1.3940x over previous
//
#include <hip/hip_runtime.h>
#include <math.h>

#define HS 8
#define E 12
#define NA 20
#define KC 4

typedef float f32x4 __attribute__((ext_vector_type(4)));
typedef short short8 __attribute__((ext_vector_type(8)));

// Precomputed, batch-independent tables:
__device__ float g_QKVT[54 * 48];                  // per-card qkv table
__device__ float g_abias[NA * 32];                 // per-action folded score bias
__device__ __align__(16) short g_dpB[2 * 4 * 64 * 16];   // dp_w1 B-frags [s*4+t][lane][8hi,8lo]
__device__ __align__(16) short g_ctxB[2 * 8 * 64 * 16];  // ctx_w1 B-frags [s*8+t][lane][...]
__device__ __align__(16) short g_WtB[4 * 2 * 64 * 16];   // folded Wt B-frags [s*2+t][lane][...]

__device__ __forceinline__ void split_bf16(float f, short& hi, short& lo) {
    unsigned u = __float_as_uint(f);
    unsigned r = (u + 0x7FFFu + ((u >> 16) & 1u)) >> 16;  // RNE to bf16
    hi = (short)r;
    float fh = __uint_as_float(r << 16);
    unsigned v = __float_as_uint(f - fh);
    unsigned r2 = (v + 0x7FFFu + ((v >> 16) & 1u)) >> 16;
    lo = (short)r2;
}

__global__ void precompute_kernel(const float* __restrict__ card_emb,
                                  const int* __restrict__ aci,
                                  const float* __restrict__ ctx_w2,
                                  const float* __restrict__ ctx_b2,
                                  const float* __restrict__ sc_w1,
                                  const float* __restrict__ sc_b1,
                                  const float* __restrict__ in_w,
                                  const float* __restrict__ in_b,
                                  const float* __restrict__ ctx_w1,
                                  const float* __restrict__ dp_w1) {
    int t = blockIdx.x * 256 + threadIdx.x;
    if (t < 640) {
        // g_abias
        int a = t >> 5, j = t & 31;
        float arep[E];
#pragma unroll
        for (int k2 = 0; k2 < E; ++k2) arep[k2] = 0.f;
        float cnt = 0.f;
#pragma unroll
        for (int c = 0; c < KC; ++c) {
            int idx = aci[a * KC + c];
            if (idx != 0) {
                cnt += 1.f;
#pragma unroll
                for (int k2 = 0; k2 < E; ++k2) arep[k2] += card_emb[idx * E + k2];
            }
        }
        float inv = 1.f / fmaxf(cnt, 1.f);
        float s = sc_b1[j];
#pragma unroll
        for (int k2 = 0; k2 < E; ++k2) s += sc_w1[j * 140 + 128 + k2] * (arep[k2] * inv);
        for (int i = 0; i < 128; ++i) s += sc_w1[j * 140 + i] * ctx_b2[i];
        g_abias[t] = s;
    } else if (t < 3232) {
        // g_QKVT
        int t2 = t - 640;
        int c = t2 / 48, col = t2 % 48;
        int h = col / 12, s = col % 12;
        float val = 0.f;
        if (s < 9) {
            int r;
            if (s < 3) r = h * 3 + s;
            else if (s < 6) r = 12 + h * 3 + (s - 3);
            else r = 24 + h * 3 + (s - 6);
            val = in_b[r];
#pragma unroll
            for (int j = 0; j < 12; ++j) val += in_w[r * 12 + j] * card_emb[c * 12 + j];
        }
        g_QKVT[t2] = val;
    } else if (t < 7328) {
        // g_dpB: B[k][n] = dp_w1[col=16t+n][k], k = 32s+8g+j
        int id = t - 3232;
        int st = id >> 9, lane = (id >> 3) & 63, j = id & 7;
        int s = st >> 2, tt = st & 3;
        int g = lane >> 4, n = lane & 15;
        int k = 32 * s + 8 * g + j, col = 16 * tt + n;
        float w = (k < 54) ? dp_w1[col * 54 + k] : 0.f;
        short hi, lo;
        split_bf16(w, hi, lo);
        int base = ((st << 6) + lane) << 4;
        g_dpB[base + j] = hi;
        g_dpB[base + 8 + j] = lo;
    } else if (t < 15520) {
        // g_ctxB: B[k][n] = ctx_w1[col=16t+n][k], k = 32s+8g+j (k<36)
        int id = t - 7328;
        int st = id >> 9, lane = (id >> 3) & 63, j = id & 7;
        int s = st >> 3, tt = st & 7;
        int g = lane >> 4, n = lane & 15;
        int k = 32 * s + 8 * g + j, col = 16 * tt + n;
        float w = (k < 36) ? ctx_w1[col * 36 + k] : 0.f;
        short hi, lo;
        split_bf16(w, hi, lo);
        int base = ((st << 6) + lane) << 4;
        g_ctxB[base + j] = hi;
        g_ctxB[base + 8 + j] = lo;
    } else if (t < 19616) {
        // g_WtB: B[k][n] = Wt[m=k][j=col] = sum_i sc_w1[col][i]*ctx_w2[i][k]
        int id = t - 15520;
        int st = id >> 9, lane = (id >> 3) & 63, j = id & 7;
        int s = st >> 1, tt = st & 1;
        int g = lane >> 4, n = lane & 15;
        int k = 32 * s + 8 * g + j, col = 16 * tt + n;
        float w = 0.f;
        for (int i = 0; i < 128; ++i) w += sc_w1[col * 140 + i] * ctx_w2[i * 128 + k];
        short hi, lo;
        split_bf16(w, hi, lo);
        int base = ((st << 6) + lane) << 4;
        g_WtB[base + j] = hi;
        g_WtB[base + 8 + j] = lo;
    }
}

#define MFMA(a, b, c) __builtin_amdgcn_mfma_f32_16x16x32_bf16(a, b, c, 0, 0, 0)

// Block = 256 threads = 4 waves = 64 elements. Each wave owns 16 elements.
// Phase A: quad mapping (elem = tid>>2, q = tid&3) -> writes c36 to sS.
// MFMA phases: elem = 16w + (lane&15), g = lane>>4.
__global__ __launch_bounds__(256) void policy_kernel(
    const int* __restrict__ hand_cards, const float* __restrict__ game_state,
    const float* __restrict__ discard, const int* __restrict__ enemy_card,
    const int* __restrict__ hand_size, const int* __restrict__ num_valid,
    const float* __restrict__ enemy_emb, const float* __restrict__ out_w,
    const float* __restrict__ out_b, const float* __restrict__ gs_w1,
    const float* __restrict__ gs_b1, const float* __restrict__ gs_w2,
    const float* __restrict__ gs_b2, const float* __restrict__ dp_w2,
    const float* __restrict__ dp_b1, const float* __restrict__ dp_b2,
    const float* __restrict__ ctx_b1, const float* __restrict__ sc_w2,
    const float* __restrict__ sc_b2, float* __restrict__ out) {
    __shared__ __align__(16) float sS[64 * 68];     // c36 (feats 0..35, 36..67 zero)
    __shared__ __align__(16) float sT[4 * 16 * 36]; // per-wave transpose buffer
    __shared__ __align__(16) float sQKVT[54 * 48];
    __shared__ __align__(16) float sEN[54 * 12];
    __shared__ __align__(16) float sGS1[64 * 12];
    __shared__ __align__(16) float sGS2T[64 * 8];
    __shared__ __align__(16) float sDPW2T[64 * 12];
    __shared__ __align__(16) float sAB[NA * 36];
    __shared__ __align__(16) float sOW[144];
    __shared__ __align__(16) float sW2[32];
    __shared__ float sGSB1[64];
    __shared__ float sDPB1[64];
    __shared__ float sCB1[128];

    int tid = threadIdx.x;
    for (int i = tid; i < 54 * 48; i += 256) sQKVT[i] = g_QKVT[i];
    for (int i = tid; i < 54 * 12; i += 256) sEN[i] = enemy_emb[i];
    for (int i = tid; i < 64 * 12; i += 256) {
        int r = i / 12, c = i % 12;
        sGS1[((r & 15) * 4 + (r >> 4)) * 12 + c] = gs_w1[i];
    }
    for (int i = tid; i < 64 * 8; i += 256) {
        int r = i >> 3, c = i & 7;
        sGS2T[((r & 15) * 4 + (r >> 4)) * 8 + c] = (c < 6) ? gs_w2[c * 64 + r] : 0.f;
    }
    for (int i = tid; i < 64 * 12; i += 256) {
        int f = i / 12, c = i % 12;
        sDPW2T[i] = (c < 6) ? dp_w2[c * 64 + f] : 0.f;
    }
    for (int i = tid; i < NA * 36; i += 256) {
        int a = i / 36, c = i % 36;
        sAB[i] = (c < 32) ? g_abias[a * 32 + c] : 0.f;
    }
    if (tid < 144) sOW[tid] = out_w[tid];
    if (tid >= 160 && tid < 192) sW2[tid - 160] = sc_w2[tid - 160];
    if (tid >= 192 && tid < 256) sGSB1[tid - 192] = gs_b1[tid - 192];
    for (int i = tid; i < 64; i += 256) sDPB1[i] = dp_b1[i];
    for (int i = tid; i < 128; i += 256) sCB1[i] = ctx_b1[i];
    for (int i = tid; i < 64 * 32; i += 256) {
        int e = i >> 5, c = i & 31;
        sS[e * 68 + 36 + c] = 0.f;
    }
    __syncthreads();

    int lane = tid & 63;
    int w = tid >> 6;

    // ================= Phase A: attention + hand_ctx + enemy + gs (quad map) ====
    {
        int q = tid & 3;
        int el = tid >> 2;
        int b = blockIdx.x * 64 + el;
        int base = lane & ~3;

        int hc[HS];
        {
            const int4* hp = (const int4*)(hand_cards + (size_t)b * HS);
            int4 h0 = hp[0], h1 = hp[1];
            hc[0] = h0.x; hc[1] = h0.y; hc[2] = h0.z; hc[3] = h0.w;
            hc[4] = h1.x; hc[5] = h1.y; hc[6] = h1.z; hc[7] = h1.w;
        }
        int ec = enemy_card[b];

        float qk[HS][9];
#pragma unroll
        for (int p = 0; p < HS; ++p) {
            const float4* tp = (const float4*)&sQKVT[hc[p] * 48 + q * 12];
            float4 a0 = tp[0], a1 = tp[1], a2 = tp[2];
            qk[p][0] = a0.x; qk[p][1] = a0.y; qk[p][2] = a0.z;
            qk[p][3] = a0.w; qk[p][4] = a1.x; qk[p][5] = a1.y;
            qk[p][6] = a1.z; qk[p][7] = a1.w; qk[p][8] = a2.x;
        }
        const float scale = 0.5773502691896258f;
        float attv0 = 0.f, attv1 = 0.f, attv2 = 0.f;
#pragma unroll
        for (int p = 0; p < HS; ++p) {
            float s[HS];
            float mx = -3.0e38f;
#pragma unroll
            for (int k = 0; k < HS; ++k) {
                float t = (qk[p][0] * qk[k][3] + qk[p][1] * qk[k][4] + qk[p][2] * qk[k][5]) * scale;
                t = (hc[k] != 0) ? t : -1.0e9f;
                s[k] = t;
                mx = fmaxf(mx, t);
            }
            float sum = 0.f;
#pragma unroll
            for (int k = 0; k < HS; ++k) {
                float e = __expf(s[k] - mx);
                s[k] = e;
                sum += e;
            }
            float inv = 1.f / sum;
            float a0 = 0.f, a1 = 0.f, a2 = 0.f;
#pragma unroll
            for (int k = 0; k < HS; ++k) {
                a0 += s[k] * qk[k][6];
                a1 += s[k] * qk[k][7];
                a2 += s[k] * qk[k][8];
            }
            attv0 += a0 * inv; attv1 += a1 * inv; attv2 += a2 * inv;
        }
        float attw[12];
#pragma unroll
        for (int j = 0; j < 12; ++j) {
            float v = (j % 3 == 0) ? attv0 : ((j % 3 == 1) ? attv1 : attv2);
            attw[j] = __shfl(v, base + j / 3, 64);
        }
        {
            float invlen = 1.f / fmaxf((float)hand_size[b], 1.f);
#pragma unroll
            for (int t2 = 0; t2 < 3; ++t2) {
                int r = 3 * q + t2;
                float a = 8.f * out_b[r];
#pragma unroll
                for (int e = 0; e < 12; ++e) a += sOW[r * 12 + e] * attw[e];
                sS[el * 68 + r] = a * invlen;  // feats 0..11
            }
        }
#pragma unroll
        for (int t2 = 0; t2 < 3; ++t2)  // feats 12..23 (enemy)
            sS[el * 68 + 12 + 3 * q + t2] = sEN[ec * 12 + 3 * q + t2];

        // game_state MLP
        {
            const float4* gp = (const float4*)(game_state + (size_t)b * 12);
            float4 x0 = gp[0], x1 = gp[1], x2 = gp[2];
            float acc[6] = {0.f, 0.f, 0.f, 0.f, 0.f, 0.f};
#pragma unroll 4
            for (int jj = 0; jj < 16; ++jj) {
                const float4* wr = (const float4*)&sGS1[(jj * 4 + q) * 12];
                float4 w0 = wr[0], w1 = wr[1], w2 = wr[2];
                float h = sGSB1[q * 16 + jj];
                h += w0.x * x0.x + w0.y * x0.y + w0.z * x0.z + w0.w * x0.w;
                h += w1.x * x1.x + w1.y * x1.y + w1.z * x1.z + w1.w * x1.w;
                h += w2.x * x2.x + w2.y * x2.y + w2.z * x2.z + w2.w * x2.w;
                h = fmaxf(h, 0.f);
                const float4* w2r = (const float4*)&sGS2T[(jj * 4 + q) * 8];
                float4 wa = w2r[0], wb = w2r[1];
                acc[0] += h * wa.x; acc[1] += h * wa.y; acc[2] += h * wa.z;
                acc[3] += h * wa.w; acc[4] += h * wb.x; acc[5] += h * wb.y;
            }
#pragma unroll
            for (int c = 0; c < 6; ++c) {
                float v = acc[c];
                v += __shfl_xor(v, 1, 64);
                v += __shfl_xor(v, 2, 64);
                acc[c] = v + gs_b2[c];
            }
            if (q < 3) {  // feats 24..29
                sS[el * 68 + 24 + 2 * q + 0] = acc[2 * q + 0];
                sS[el * 68 + 24 + 2 * q + 1] = acc[2 * q + 1];
            }
        }
    }

    // ================= dp MLP via MFMA =================
    int n = lane & 15, g = lane >> 4;
    int el2 = (w << 4) + n;
    int b2 = blockIdx.x * 64 + el2;
    {
        const float* drow = discard + (size_t)b2 * 54;
        float xa[16];
        {
            const float2* p = (const float2*)(drow + 8 * g);
            float2 v0 = p[0], v1 = p[1], v2 = p[2], v3 = p[3];
            xa[0] = v0.x; xa[1] = v0.y; xa[2] = v1.x; xa[3] = v1.y;
            xa[4] = v2.x; xa[5] = v2.y; xa[6] = v3.x; xa[7] = v3.y;
        }
#pragma unroll
        for (int j = 0; j < 8; ++j) {
            int k = 32 + 8 * g + j;
            xa[8 + j] = (k < 54) ? drow[k] : 0.f;
        }
        short8 ahi0, alo0, ahi1, alo1;
#pragma unroll
        for (int j = 0; j < 8; ++j) {
            short h, l;
            split_bf16(xa[j], h, l);     ahi0[j] = h; alo0[j] = l;
            split_bf16(xa[8 + j], h, l); ahi1[j] = h; alo1[j] = l;
        }
        f32x4 dacc[4];
#pragma unroll
        for (int t = 0; t < 4; ++t) {
            float bv = sDPB1[16 * t + n];
            f32x4 cc = {bv, bv, bv, bv};
            dacc[t] = cc;
        }
#pragma unroll
        for (int t = 0; t < 4; ++t) {
#pragma unroll
            for (int s = 0; s < 2; ++s) {
                const short8* bp = (const short8*)&g_dpB[(((s * 4 + t) << 6) + lane) << 4];
                short8 bh = bp[0], bl = bp[1];
                short8 ah = s ? ahi1 : ahi0;
                short8 al = s ? alo1 : alo0;
                dacc[t] = MFMA(ah, bh, dacc[t]);
                dacc[t] = MFMA(ah, bl, dacc[t]);
                dacc[t] = MFMA(al, bh, dacc[t]);
            }
        }
        // dp layer 2 on VALU + cross-lane reduce over n
        float part[4][6];
#pragma unroll
        for (int r = 0; r < 4; ++r)
#pragma unroll
            for (int c = 0; c < 6; ++c) part[r][c] = 0.f;
#pragma unroll
        for (int t = 0; t < 4; ++t) {
            const float* wrow = &sDPW2T[(16 * t + n) * 12];
            float4 wa = *(const float4*)wrow;
            float2 wb = *(const float2*)(wrow + 4);
#pragma unroll
            for (int r = 0; r < 4; ++r) {
                float h = fmaxf(dacc[t][r], 0.f);
                part[r][0] += h * wa.x; part[r][1] += h * wa.y; part[r][2] += h * wa.z;
                part[r][3] += h * wa.w; part[r][4] += h * wb.x; part[r][5] += h * wb.y;
            }
        }
#pragma unroll
        for (int r = 0; r < 4; ++r)
#pragma unroll
            for (int c = 0; c < 6; ++c) {
                float v = part[r][c];
                v += __shfl_xor(v, 1, 64);
                v += __shfl_xor(v, 2, 64);
                v += __shfl_xor(v, 4, 64);
                v += __shfl_xor(v, 8, 64);
                part[r][c] = v;
            }
        if (n < 6) {
#pragma unroll
            for (int r = 0; r < 4; ++r) {
                float dval = part[r][0];
                dval = (n == 1) ? part[r][1] : dval;
                dval = (n == 2) ? part[r][2] : dval;
                dval = (n == 3) ? part[r][3] : dval;
                dval = (n == 4) ? part[r][4] : dval;
                dval = (n == 5) ? part[r][5] : dval;
                sS[((w << 4) + (g << 2) + r) * 68 + 30 + n] = dval + dp_b2[n];
            }
        }
    }

    asm volatile("s_waitcnt lgkmcnt(0)" ::: "memory");

    // ================= ctx1 + folded-Wt via MFMA =================
    float* sTT = sT + w * 576;
    f32x4 uacc[2];
    {
        f32x4 z = {0.f, 0.f, 0.f, 0.f};
        uacc[0] = z; uacc[1] = z;
    }
    {
        const float* arow = sS + el2 * 68;
        float ca[16];
        {
            const float4* ap0 = (const float4*)(arow + 8 * g);
            float4 a0 = ap0[0], a1 = ap0[1];
            const float4* ap1 = (const float4*)(arow + 32 + 8 * g);
            float4 a2 = ap1[0], a3 = ap1[1];
            ca[0] = a0.x; ca[1] = a0.y; ca[2] = a0.z; ca[3] = a0.w;
            ca[4] = a1.x; ca[5] = a1.y; ca[6] = a1.z; ca[7] = a1.w;
            ca[8] = a2.x; ca[9] = a2.y; ca[10] = a2.z; ca[11] = a2.w;
            ca[12] = a3.x; ca[13] = a3.y; ca[14] = a3.z; ca[15] = a3.w;
        }
        short8 cahi0, calo0, cahi1, calo1;
#pragma unroll
        for (int j = 0; j < 8; ++j) {
            short h, l;
            split_bf16(ca[j], h, l);     cahi0[j] = h; calo0[j] = l;
            split_bf16(ca[8 + j], h, l); cahi1[j] = h; calo1[j] = l;
        }
#pragma unroll
        for (int p = 0; p < 4; ++p) {
            f32x4 cacc[2];
#pragma unroll
            for (int t2 = 0; t2 < 2; ++t2) {
                float bv = sCB1[(p * 2 + t2) * 16 + n];
                f32x4 cc = {bv, bv, bv, bv};
                cacc[t2] = cc;
            }
#pragma unroll
            for (int t2 = 0; t2 < 2; ++t2) {
                int tt = p * 2 + t2;
#pragma unroll
                for (int s = 0; s < 2; ++s) {
                    const short8* bp = (const short8*)&g_ctxB[(((s * 8 + tt) << 6) + lane) << 4];
                    short8 bh = bp[0], bl = bp[1];
                    short8 ah = s ? cahi1 : cahi0;
                    short8 al = s ? calo1 : calo0;
                    cacc[t2] = MFMA(ah, bh, cacc[t2]);
                    cacc[t2] = MFMA(ah, bl, cacc[t2]);
                    cacc[t2] = MFMA(al, bh, cacc[t2]);
                }
            }
            // transpose relu(h) chunk (32 feats) through per-wave LDS
#pragma unroll
            for (int t2 = 0; t2 < 2; ++t2)
#pragma unroll
                for (int r = 0; r < 4; ++r)
                    sTT[((g << 2) + r) * 36 + t2 * 16 + n] = fmaxf(cacc[t2][r], 0.f);
            asm volatile("s_waitcnt lgkmcnt(0)" ::: "memory");
            float ha[8];
            {
                const float4* hp = (const float4*)&sTT[n * 36 + 8 * g];
                float4 h0 = hp[0], h1 = hp[1];
                ha[0] = h0.x; ha[1] = h0.y; ha[2] = h0.z; ha[3] = h0.w;
                ha[4] = h1.x; ha[5] = h1.y; ha[6] = h1.z; ha[7] = h1.w;
            }
            short8 whi, wlo;
#pragma unroll
            for (int j = 0; j < 8; ++j) {
                short h, l;
                split_bf16(ha[j], h, l);
                whi[j] = h; wlo[j] = l;
            }
#pragma unroll
            for (int t2 = 0; t2 < 2; ++t2) {
                const short8* bp = (const short8*)&g_WtB[(((p * 2 + t2) << 6) + lane) << 4];
                short8 bh = bp[0], bl = bp[1];
                uacc[t2] = MFMA(whi, bh, uacc[t2]);
                uacc[t2] = MFMA(whi, bl, uacc[t2]);
                uacc[t2] = MFMA(wlo, bh, uacc[t2]);
            }
            asm volatile("s_waitcnt lgkmcnt(0)" ::: "memory");
        }
    }

    // ================= score layer =================
    {
#pragma unroll
        for (int t2 = 0; t2 < 2; ++t2)
#pragma unroll
            for (int r = 0; r < 4; ++r)
                sTT[((g << 2) + r) * 36 + t2 * 16 + n] = uacc[t2][r];
        asm volatile("s_waitcnt lgkmcnt(0)" ::: "memory");
        float uu[32];
        {
            const float4* up = (const float4*)&sTT[n * 36];
#pragma unroll
            for (int j8 = 0; j8 < 8; ++j8) {
                float4 v = up[j8];
                uu[4 * j8 + 0] = v.x; uu[4 * j8 + 1] = v.y;
                uu[4 * j8 + 2] = v.z; uu[4 * j8 + 3] = v.w;
            }
        }
        float w2v[32];
        {
            const float4* wp = (const float4*)sW2;
#pragma unroll
            for (int j8 = 0; j8 < 8; ++j8) {
                float4 v = wp[j8];
                w2v[4 * j8 + 0] = v.x; w2v[4 * j8 + 1] = v.y;
                w2v[4 * j8 + 2] = v.z; w2v[4 * j8 + 3] = v.w;
            }
        }
        int nva = num_valid[0];
        float sb2 = sc_b2[0];
#pragma unroll
        for (int t = 0; t < 5; ++t) {
            int a = g * 5 + t;
            const float4* ab = (const float4*)&sAB[a * 36];
            float s = sb2;
#pragma unroll
            for (int j8 = 0; j8 < 8; ++j8) {
                float4 av = ab[j8];
                s += w2v[4 * j8 + 0] * fmaxf(uu[4 * j8 + 0] + av.x, 0.f);
                s += w2v[4 * j8 + 1] * fmaxf(uu[4 * j8 + 1] + av.y, 0.f);
                s += w2v[4 * j8 + 2] * fmaxf(uu[4 * j8 + 2] + av.z, 0.f);
                s += w2v[4 * j8 + 3] * fmaxf(uu[4 * j8 + 3] + av.w, 0.f);
            }
            out[(size_t)b2 * NA + a] = (a < nva) ? s : -1.0e8f;
        }
    }
}

extern "C" void kernel_launch(void* const* d_in, const int* in_sizes, int n_in,
                              void* d_out, int out_size, void* d_ws, size_t ws_size,
                              hipStream_t stream) {
    const int* hand_cards = (const int*)d_in[0];
    const float* game_state = (const float*)d_in[1];
    const float* discard = (const float*)d_in[2];
    const int* enemy_card = (const int*)d_in[3];
    const int* hand_size = (const int*)d_in[4];
    const int* aci = (const int*)d_in[5];
    const int* num_valid = (const int*)d_in[6];
    const float* card_emb = (const float*)d_in[7];
    const float* enemy_emb = (const float*)d_in[8];
    const float* in_w = (const float*)d_in[9];
    const float* in_b = (const float*)d_in[10];
    const float* out_w = (const float*)d_in[11];
    const float* out_b = (const float*)d_in[12];
    const float* gs_w1 = (const float*)d_in[13];
    const float* gs_b1 = (const float*)d_in[14];
    const float* gs_w2 = (const float*)d_in[15];
    const float* gs_b2 = (const float*)d_in[16];
    const float* dp_w1 = (const float*)d_in[17];
    const float* dp_b1 = (const float*)d_in[18];
    const float* dp_w2 = (const float*)d_in[19];
    const float* dp_b2 = (const float*)d_in[20];
    const float* ctx_w1 = (const float*)d_in[21];
    const float* ctx_b1 = (const float*)d_in[22];
    const float* ctx_w2 = (const float*)d_in[23];
    const float* ctx_b2 = (const float*)d_in[24];
    const float* sc_w1 = (const float*)d_in[25];
    const float* sc_b1 = (const float*)d_in[26];
    const float* sc_w2 = (const float*)d_in[27];
    const float* sc_b2 = (const float*)d_in[28];

    int B = in_sizes[0] / HS;

    precompute_kernel<<<77, 256, 0, stream>>>(card_emb, aci, ctx_w2, ctx_b2, sc_w1, sc_b1,
                                              in_w, in_b, ctx_w1, dp_w1);
    policy_kernel<<<B / 64, 256, 0, stream>>>(
        hand_cards, game_state, discard, enemy_card, hand_size, num_valid,
        enemy_emb, out_w, out_b, gs_w1, gs_b1, gs_w2, gs_b2, dp_w2, dp_b1, dp_b2,
        ctx_b1, sc_w2, sc_b2, (float*)d_out);
}

// Round 5
// 55.019 us; speedup vs baseline: 3.8620x; 1.0133x over previous
//
#include <hip/hip_runtime.h>
#include <math.h>

#define HS 8
#define E 12
#define NA 20
#define KC 4

typedef float f32x4 __attribute__((ext_vector_type(4)));
typedef short short8 __attribute__((ext_vector_type(8)));

// Precomputed, batch-independent tables:
__device__ float g_QKVT[54 * 48];                  // per-card qkv table
__device__ float g_abias[NA * 32];                 // per-action folded score bias
__device__ __align__(16) short g_dpB[2 * 4 * 64 * 16];   // dp_w1 B-frags [s*4+t][lane][8hi,8lo]
__device__ __align__(16) short g_ctxB[2 * 8 * 64 * 16];  // ctx_w1 B-frags [s*8+t][lane][...]
__device__ __align__(16) short g_WtB[4 * 2 * 64 * 16];   // folded Wt B-frags [s*2+t][lane][...]

__device__ __forceinline__ void split_bf16(float f, short& hi, short& lo) {
    unsigned u = __float_as_uint(f);
    unsigned r = (u + 0x7FFFu + ((u >> 16) & 1u)) >> 16;  // RNE to bf16
    hi = (short)r;
    float fh = __uint_as_float(r << 16);
    unsigned v = __float_as_uint(f - fh);
    unsigned r2 = (v + 0x7FFFu + ((v >> 16) & 1u)) >> 16;
    lo = (short)r2;
}

__global__ void precompute_kernel(const float* __restrict__ card_emb,
                                  const int* __restrict__ aci,
                                  const float* __restrict__ ctx_w2,
                                  const float* __restrict__ ctx_b2,
                                  const float* __restrict__ sc_w1,
                                  const float* __restrict__ sc_b1,
                                  const float* __restrict__ in_w,
                                  const float* __restrict__ in_b,
                                  const float* __restrict__ ctx_w1,
                                  const float* __restrict__ dp_w1) {
    int t = blockIdx.x * 256 + threadIdx.x;
    if (t < 640) {
        // g_abias
        int a = t >> 5, j = t & 31;
        float arep[E];
#pragma unroll
        for (int k2 = 0; k2 < E; ++k2) arep[k2] = 0.f;
        float cnt = 0.f;
#pragma unroll
        for (int c = 0; c < KC; ++c) {
            int idx = aci[a * KC + c];
            if (idx != 0) {
                cnt += 1.f;
#pragma unroll
                for (int k2 = 0; k2 < E; ++k2) arep[k2] += card_emb[idx * E + k2];
            }
        }
        float inv = 1.f / fmaxf(cnt, 1.f);
        float s = sc_b1[j];
#pragma unroll
        for (int k2 = 0; k2 < E; ++k2) s += sc_w1[j * 140 + 128 + k2] * (arep[k2] * inv);
        for (int i = 0; i < 128; ++i) s += sc_w1[j * 140 + i] * ctx_b2[i];
        g_abias[t] = s;
    } else if (t < 3232) {
        // g_QKVT
        int t2 = t - 640;
        int c = t2 / 48, col = t2 % 48;
        int h = col / 12, s = col % 12;
        float val = 0.f;
        if (s < 9) {
            int r;
            if (s < 3) r = h * 3 + s;
            else if (s < 6) r = 12 + h * 3 + (s - 3);
            else r = 24 + h * 3 + (s - 6);
            val = in_b[r];
#pragma unroll
            for (int j = 0; j < 12; ++j) val += in_w[r * 12 + j] * card_emb[c * 12 + j];
        }
        g_QKVT[t2] = val;
    } else if (t < 7328) {
        // g_dpB: B[k][n] = dp_w1[col=16t+n][k], k = 32s+8g+j
        int id = t - 3232;
        int st = id >> 9, lane = (id >> 3) & 63, j = id & 7;
        int s = st >> 2, tt = st & 3;
        int g = lane >> 4, n = lane & 15;
        int k = 32 * s + 8 * g + j, col = 16 * tt + n;
        float w = (k < 54) ? dp_w1[col * 54 + k] : 0.f;
        short hi, lo;
        split_bf16(w, hi, lo);
        int base = ((st << 6) + lane) << 4;
        g_dpB[base + j] = hi;
        g_dpB[base + 8 + j] = lo;
    } else if (t < 15520) {
        // g_ctxB: B[k][n] = ctx_w1[col=16t+n][k], k = 32s+8g+j (k<36)
        int id = t - 7328;
        int st = id >> 9, lane = (id >> 3) & 63, j = id & 7;
        int s = st >> 3, tt = st & 7;
        int g = lane >> 4, n = lane & 15;
        int k = 32 * s + 8 * g + j, col = 16 * tt + n;
        float w = (k < 36) ? ctx_w1[col * 36 + k] : 0.f;
        short hi, lo;
        split_bf16(w, hi, lo);
        int base = ((st << 6) + lane) << 4;
        g_ctxB[base + j] = hi;
        g_ctxB[base + 8 + j] = lo;
    } else if (t < 19616) {
        // g_WtB: B[k][n] = Wt[m=k][j=col] = sum_i sc_w1[col][i]*ctx_w2[i][k]
        int id = t - 15520;
        int st = id >> 9, lane = (id >> 3) & 63, j = id & 7;
        int s = st >> 1, tt = st & 1;
        int g = lane >> 4, n = lane & 15;
        int k = 32 * s + 8 * g + j, col = 16 * tt + n;
        float w = 0.f;
        for (int i = 0; i < 128; ++i) w += sc_w1[col * 140 + i] * ctx_w2[i * 128 + k];
        short hi, lo;
        split_bf16(w, hi, lo);
        int base = ((st << 6) + lane) << 4;
        g_WtB[base + j] = hi;
        g_WtB[base + 8 + j] = lo;
    }
}

#define MFMA(a, b, c) __builtin_amdgcn_mfma_f32_16x16x32_bf16(a, b, c, 0, 0, 0)

// Block = 256 threads = 4 waves = 64 elements. Each wave owns 16 elements
// (phase A: el = tid>>2 in [16w,16w+15]; MFMA phases: el2 = 16w + (lane&15)).
// sS stride 52: 52%32=20, gcd(20,32)=4 -> 2-way LDS conflicts only (free).
// sU: union of QKVT table (phase A) and per-wave transpose buffer (MFMA phases),
// separated by one __syncthreads.
__global__ __launch_bounds__(256) void policy_kernel(
    const int* __restrict__ hand_cards, const float* __restrict__ game_state,
    const float* __restrict__ discard, const int* __restrict__ enemy_card,
    const int* __restrict__ hand_size, const int* __restrict__ num_valid,
    const float* __restrict__ enemy_emb, const float* __restrict__ out_w,
    const float* __restrict__ out_b, const float* __restrict__ gs_w1,
    const float* __restrict__ gs_b1, const float* __restrict__ gs_w2,
    const float* __restrict__ gs_b2, const float* __restrict__ dp_w2,
    const float* __restrict__ dp_b1, const float* __restrict__ dp_b2,
    const float* __restrict__ ctx_b1, const float* __restrict__ sc_w2,
    const float* __restrict__ sc_b2, float* __restrict__ out) {
    __shared__ __align__(16) float sS[64 * 52];     // c36 (feats 0..35, 36..51 zero)
    __shared__ __align__(16) float sU[54 * 48];     // QKVT, then per-wave transpose buf
    __shared__ __align__(16) float sEN[54 * 12];
    __shared__ __align__(16) float sGS1[64 * 12];
    __shared__ __align__(16) float sGS2T[64 * 8];
    __shared__ __align__(16) float sDPW2T[64 * 12];
    __shared__ __align__(16) float sAB[NA * 36];
    __shared__ __align__(16) float sOW[144];
    __shared__ __align__(16) float sW2[32];
    __shared__ float sGSB1[64];
    __shared__ float sDPB1[64];
    __shared__ float sCB1[128];

    int tid = threadIdx.x;
    for (int i = tid; i < 54 * 48; i += 256) sU[i] = g_QKVT[i];
    for (int i = tid; i < 54 * 12; i += 256) sEN[i] = enemy_emb[i];
    for (int i = tid; i < 64 * 12; i += 256) {
        int r = i / 12, c = i % 12;
        sGS1[((r & 15) * 4 + (r >> 4)) * 12 + c] = gs_w1[i];
    }
    for (int i = tid; i < 64 * 8; i += 256) {
        int r = i >> 3, c = i & 7;
        sGS2T[((r & 15) * 4 + (r >> 4)) * 8 + c] = (c < 6) ? gs_w2[c * 64 + r] : 0.f;
    }
    for (int i = tid; i < 64 * 12; i += 256) {
        int f = i / 12, c = i % 12;
        sDPW2T[i] = (c < 6) ? dp_w2[c * 64 + f] : 0.f;
    }
    for (int i = tid; i < NA * 36; i += 256) {
        int a = i / 36, c = i % 36;
        sAB[i] = (c < 32) ? g_abias[a * 32 + c] : 0.f;
    }
    if (tid < 144) sOW[tid] = out_w[tid];
    if (tid >= 160 && tid < 192) sW2[tid - 160] = sc_w2[tid - 160];
    if (tid >= 192 && tid < 256) sGSB1[tid - 192] = gs_b1[tid - 192];
    for (int i = tid; i < 64; i += 256) sDPB1[i] = dp_b1[i];
    for (int i = tid; i < 128; i += 256) sCB1[i] = ctx_b1[i];
    for (int i = tid; i < 64 * 16; i += 256) {
        int e = i >> 4, c = i & 15;
        sS[e * 52 + 36 + c] = 0.f;
    }
    __syncthreads();

    int lane = tid & 63;
    int w = tid >> 6;

    // ================= Phase A: attention + hand_ctx + enemy + gs (quad map) ====
    {
        int q = tid & 3;
        int el = tid >> 2;
        int b = blockIdx.x * 64 + el;
        int base = lane & ~3;

        int hc[HS];
        {
            const int4* hp = (const int4*)(hand_cards + (size_t)b * HS);
            int4 h0 = hp[0], h1 = hp[1];
            hc[0] = h0.x; hc[1] = h0.y; hc[2] = h0.z; hc[3] = h0.w;
            hc[4] = h1.x; hc[5] = h1.y; hc[6] = h1.z; hc[7] = h1.w;
        }
        int ec = enemy_card[b];

        float qk[HS][9];
#pragma unroll
        for (int p = 0; p < HS; ++p) {
            const float4* tp = (const float4*)&sU[hc[p] * 48 + q * 12];
            float4 a0 = tp[0], a1 = tp[1], a2 = tp[2];
            qk[p][0] = a0.x; qk[p][1] = a0.y; qk[p][2] = a0.z;
            qk[p][3] = a0.w; qk[p][4] = a1.x; qk[p][5] = a1.y;
            qk[p][6] = a1.z; qk[p][7] = a1.w; qk[p][8] = a2.x;
        }
        const float scale = 0.5773502691896258f;
        float attv0 = 0.f, attv1 = 0.f, attv2 = 0.f;
#pragma unroll
        for (int p = 0; p < HS; ++p) {
            float s[HS];
            float mx = -3.0e38f;
#pragma unroll
            for (int k = 0; k < HS; ++k) {
                float t = (qk[p][0] * qk[k][3] + qk[p][1] * qk[k][4] + qk[p][2] * qk[k][5]) * scale;
                t = (hc[k] != 0) ? t : -1.0e9f;
                s[k] = t;
                mx = fmaxf(mx, t);
            }
            float sum = 0.f;
#pragma unroll
            for (int k = 0; k < HS; ++k) {
                float e = __expf(s[k] - mx);
                s[k] = e;
                sum += e;
            }
            float inv = 1.f / sum;
            float a0 = 0.f, a1 = 0.f, a2 = 0.f;
#pragma unroll
            for (int k = 0; k < HS; ++k) {
                a0 += s[k] * qk[k][6];
                a1 += s[k] * qk[k][7];
                a2 += s[k] * qk[k][8];
            }
            attv0 += a0 * inv; attv1 += a1 * inv; attv2 += a2 * inv;
        }
        float attw[12];
#pragma unroll
        for (int j = 0; j < 12; ++j) {
            float v = (j % 3 == 0) ? attv0 : ((j % 3 == 1) ? attv1 : attv2);
            attw[j] = __shfl(v, base + j / 3, 64);
        }
        {
            float invlen = 1.f / fmaxf((float)hand_size[b], 1.f);
#pragma unroll
            for (int t2 = 0; t2 < 3; ++t2) {
                int r = 3 * q + t2;
                float a = 8.f * out_b[r];
#pragma unroll
                for (int e = 0; e < 12; ++e) a += sOW[r * 12 + e] * attw[e];
                sS[el * 52 + r] = a * invlen;  // feats 0..11
            }
        }
#pragma unroll
        for (int t2 = 0; t2 < 3; ++t2)  // feats 12..23 (enemy)
            sS[el * 52 + 12 + 3 * q + t2] = sEN[ec * 12 + 3 * q + t2];

        // game_state MLP
        {
            const float4* gp = (const float4*)(game_state + (size_t)b * 12);
            float4 x0 = gp[0], x1 = gp[1], x2 = gp[2];
            float acc[6] = {0.f, 0.f, 0.f, 0.f, 0.f, 0.f};
#pragma unroll 4
            for (int jj = 0; jj < 16; ++jj) {
                const float4* wr = (const float4*)&sGS1[(jj * 4 + q) * 12];
                float4 w0 = wr[0], w1 = wr[1], w2 = wr[2];
                float h = sGSB1[q * 16 + jj];
                h += w0.x * x0.x + w0.y * x0.y + w0.z * x0.z + w0.w * x0.w;
                h += w1.x * x1.x + w1.y * x1.y + w1.z * x1.z + w1.w * x1.w;
                h += w2.x * x2.x + w2.y * x2.y + w2.z * x2.z + w2.w * x2.w;
                h = fmaxf(h, 0.f);
                const float4* w2r = (const float4*)&sGS2T[(jj * 4 + q) * 8];
                float4 wa = w2r[0], wb = w2r[1];
                acc[0] += h * wa.x; acc[1] += h * wa.y; acc[2] += h * wa.z;
                acc[3] += h * wa.w; acc[4] += h * wb.x; acc[5] += h * wb.y;
            }
#pragma unroll
            for (int c = 0; c < 6; ++c) {
                float v = acc[c];
                v += __shfl_xor(v, 1, 64);
                v += __shfl_xor(v, 2, 64);
                acc[c] = v + gs_b2[c];
            }
            if (q < 3) {  // feats 24..29
                sS[el * 52 + 24 + 2 * q + 0] = acc[2 * q + 0];
                sS[el * 52 + 24 + 2 * q + 1] = acc[2 * q + 1];
            }
        }
    }

    // All waves done reading sU-as-QKVT before any wave reuses it as transpose buf.
    __syncthreads();

    // ================= dp MLP via MFMA =================
    int n = lane & 15, g = lane >> 4;
    int el2 = (w << 4) + n;
    int b2 = blockIdx.x * 64 + el2;
    {
        const float* drow = discard + (size_t)b2 * 54;
        float xa[16];
        {
            const float2* p = (const float2*)(drow + 8 * g);
            float2 v0 = p[0], v1 = p[1], v2 = p[2], v3 = p[3];
            xa[0] = v0.x; xa[1] = v0.y; xa[2] = v1.x; xa[3] = v1.y;
            xa[4] = v2.x; xa[5] = v2.y; xa[6] = v3.x; xa[7] = v3.y;
        }
#pragma unroll
        for (int j = 0; j < 8; ++j) {
            int k = 32 + 8 * g + j;
            xa[8 + j] = (k < 54) ? drow[k] : 0.f;
        }
        short8 ahi0, alo0, ahi1, alo1;
#pragma unroll
        for (int j = 0; j < 8; ++j) {
            short h, l;
            split_bf16(xa[j], h, l);     ahi0[j] = h; alo0[j] = l;
            split_bf16(xa[8 + j], h, l); ahi1[j] = h; alo1[j] = l;
        }
        f32x4 dacc[4];
#pragma unroll
        for (int t = 0; t < 4; ++t) {
            float bv = sDPB1[16 * t + n];
            f32x4 cc = {bv, bv, bv, bv};
            dacc[t] = cc;
        }
#pragma unroll
        for (int t = 0; t < 4; ++t) {
#pragma unroll
            for (int s = 0; s < 2; ++s) {
                const short8* bp = (const short8*)&g_dpB[(((s * 4 + t) << 6) + lane) << 4];
                short8 bh = bp[0], bl = bp[1];
                short8 ah = s ? ahi1 : ahi0;
                short8 al = s ? alo1 : alo0;
                dacc[t] = MFMA(ah, bh, dacc[t]);
                dacc[t] = MFMA(ah, bl, dacc[t]);
                dacc[t] = MFMA(al, bh, dacc[t]);
            }
        }
        // dp layer 2 on VALU + cross-lane reduce over n
        float part[4][6];
#pragma unroll
        for (int r = 0; r < 4; ++r)
#pragma unroll
            for (int c = 0; c < 6; ++c) part[r][c] = 0.f;
#pragma unroll
        for (int t = 0; t < 4; ++t) {
            const float* wrow = &sDPW2T[(16 * t + n) * 12];
            float4 wa = *(const float4*)wrow;
            float2 wb = *(const float2*)(wrow + 4);
#pragma unroll
            for (int r = 0; r < 4; ++r) {
                float h = fmaxf(dacc[t][r], 0.f);
                part[r][0] += h * wa.x; part[r][1] += h * wa.y; part[r][2] += h * wa.z;
                part[r][3] += h * wa.w; part[r][4] += h * wb.x; part[r][5] += h * wb.y;
            }
        }
#pragma unroll
        for (int r = 0; r < 4; ++r)
#pragma unroll
            for (int c = 0; c < 6; ++c) {
                float v = part[r][c];
                v += __shfl_xor(v, 1, 64);
                v += __shfl_xor(v, 2, 64);
                v += __shfl_xor(v, 4, 64);
                v += __shfl_xor(v, 8, 64);
                part[r][c] = v;
            }
        if (n < 6) {
#pragma unroll
            for (int r = 0; r < 4; ++r) {
                float dval = part[r][0];
                dval = (n == 1) ? part[r][1] : dval;
                dval = (n == 2) ? part[r][2] : dval;
                dval = (n == 3) ? part[r][3] : dval;
                dval = (n == 4) ? part[r][4] : dval;
                dval = (n == 5) ? part[r][5] : dval;
                sS[((w << 4) + (g << 2) + r) * 52 + 30 + n] = dval + dp_b2[n];
            }
        }
    }

    asm volatile("s_waitcnt lgkmcnt(0)" ::: "memory");

    // ================= ctx1 + folded-Wt via MFMA =================
    float* sTT = sU + w * 576;
    f32x4 uacc[2];
    {
        f32x4 z = {0.f, 0.f, 0.f, 0.f};
        uacc[0] = z; uacc[1] = z;
    }
    {
        const float* arow = sS + el2 * 52;
        float ca[16];
        {
            const float4* ap0 = (const float4*)(arow + 8 * g);
            float4 a0 = ap0[0], a1 = ap0[1];
            const float4* ap1 = (const float4*)(arow + 32 + 8 * g);
            float4 a2 = ap1[0], a3 = ap1[1];
            ca[0] = a0.x; ca[1] = a0.y; ca[2] = a0.z; ca[3] = a0.w;
            ca[4] = a1.x; ca[5] = a1.y; ca[6] = a1.z; ca[7] = a1.w;
            ca[8] = a2.x; ca[9] = a2.y; ca[10] = a2.z; ca[11] = a2.w;
            ca[12] = a3.x; ca[13] = a3.y; ca[14] = a3.z; ca[15] = a3.w;
        }
        short8 cahi0, calo0, cahi1, calo1;
#pragma unroll
        for (int j = 0; j < 8; ++j) {
            short h, l;
            split_bf16(ca[j], h, l);     cahi0[j] = h; calo0[j] = l;
            split_bf16(ca[8 + j], h, l); cahi1[j] = h; calo1[j] = l;
        }
#pragma unroll
        for (int p = 0; p < 4; ++p) {
            f32x4 cacc[2];
#pragma unroll
            for (int t2 = 0; t2 < 2; ++t2) {
                float bv = sCB1[(p * 2 + t2) * 16 + n];
                f32x4 cc = {bv, bv, bv, bv};
                cacc[t2] = cc;
            }
#pragma unroll
            for (int t2 = 0; t2 < 2; ++t2) {
                int tt = p * 2 + t2;
#pragma unroll
                for (int s = 0; s < 2; ++s) {
                    const short8* bp = (const short8*)&g_ctxB[(((s * 8 + tt) << 6) + lane) << 4];
                    short8 bh = bp[0], bl = bp[1];
                    short8 ah = s ? cahi1 : cahi0;
                    short8 al = s ? calo1 : calo0;
                    cacc[t2] = MFMA(ah, bh, cacc[t2]);
                    cacc[t2] = MFMA(ah, bl, cacc[t2]);
                    cacc[t2] = MFMA(al, bh, cacc[t2]);
                }
            }
            // transpose relu(h) chunk (32 feats) through per-wave LDS
#pragma unroll
            for (int t2 = 0; t2 < 2; ++t2)
#pragma unroll
                for (int r = 0; r < 4; ++r)
                    sTT[((g << 2) + r) * 36 + t2 * 16 + n] = fmaxf(cacc[t2][r], 0.f);
            asm volatile("s_waitcnt lgkmcnt(0)" ::: "memory");
            float ha[8];
            {
                const float4* hp = (const float4*)&sTT[n * 36 + 8 * g];
                float4 h0 = hp[0], h1 = hp[1];
                ha[0] = h0.x; ha[1] = h0.y; ha[2] = h0.z; ha[3] = h0.w;
                ha[4] = h1.x; ha[5] = h1.y; ha[6] = h1.z; ha[7] = h1.w;
            }
            short8 whi, wlo;
#pragma unroll
            for (int j = 0; j < 8; ++j) {
                short h, l;
                split_bf16(ha[j], h, l);
                whi[j] = h; wlo[j] = l;
            }
#pragma unroll
            for (int t2 = 0; t2 < 2; ++t2) {
                const short8* bp = (const short8*)&g_WtB[(((p * 2 + t2) << 6) + lane) << 4];
                short8 bh = bp[0], bl = bp[1];
                uacc[t2] = MFMA(whi, bh, uacc[t2]);
                uacc[t2] = MFMA(whi, bl, uacc[t2]);
                uacc[t2] = MFMA(wlo, bh, uacc[t2]);
            }
            asm volatile("s_waitcnt lgkmcnt(0)" ::: "memory");
        }
    }

    // ================= score layer =================
    {
#pragma unroll
        for (int t2 = 0; t2 < 2; ++t2)
#pragma unroll
            for (int r = 0; r < 4; ++r)
                sTT[((g << 2) + r) * 36 + t2 * 16 + n] = uacc[t2][r];
        asm volatile("s_waitcnt lgkmcnt(0)" ::: "memory");
        float uu[32];
        {
            const float4* up = (const float4*)&sTT[n * 36];
#pragma unroll
            for (int j8 = 0; j8 < 8; ++j8) {
                float4 v = up[j8];
                uu[4 * j8 + 0] = v.x; uu[4 * j8 + 1] = v.y;
                uu[4 * j8 + 2] = v.z; uu[4 * j8 + 3] = v.w;
            }
        }
        float w2v[32];
        {
            const float4* wp = (const float4*)sW2;
#pragma unroll
            for (int j8 = 0; j8 < 8; ++j8) {
                float4 v = wp[j8];
                w2v[4 * j8 + 0] = v.x; w2v[4 * j8 + 1] = v.y;
                w2v[4 * j8 + 2] = v.z; w2v[4 * j8 + 3] = v.w;
            }
        }
        int nva = num_valid[0];
        float sb2 = sc_b2[0];
#pragma unroll
        for (int t = 0; t < 5; ++t) {
            int a = g * 5 + t;
            const float4* ab = (const float4*)&sAB[a * 36];
            float s = sb2;
#pragma unroll
            for (int j8 = 0; j8 < 8; ++j8) {
                float4 av = ab[j8];
                s += w2v[4 * j8 + 0] * fmaxf(uu[4 * j8 + 0] + av.x, 0.f);
                s += w2v[4 * j8 + 1] * fmaxf(uu[4 * j8 + 1] + av.y, 0.f);
                s += w2v[4 * j8 + 2] * fmaxf(uu[4 * j8 + 2] + av.z, 0.f);
                s += w2v[4 * j8 + 3] * fmaxf(uu[4 * j8 + 3] + av.w, 0.f);
            }
            out[(size_t)b2 * NA + a] = (a < nva) ? s : -1.0e8f;
        }
    }
}

extern "C" void kernel_launch(void* const* d_in, const int* in_sizes, int n_in,
                              void* d_out, int out_size, void* d_ws, size_t ws_size,
                              hipStream_t stream) {
    const int* hand_cards = (const int*)d_in[0];
    const float* game_state = (const float*)d_in[1];
    const float* discard = (const float*)d_in[2];
    const int* enemy_card = (const int*)d_in[3];
    const int* hand_size = (const int*)d_in[4];
    const int* aci = (const int*)d_in[5];
    const int* num_valid = (const int*)d_in[6];
    const float* card_emb = (const float*)d_in[7];
    const float* enemy_emb = (const float*)d_in[8];
    const float* in_w = (const float*)d_in[9];
    const float* in_b = (const float*)d_in[10];
    const float* out_w = (const float*)d_in[11];
    const float* out_b = (const float*)d_in[12];
    const float* gs_w1 = (const float*)d_in[13];
    const float* gs_b1 = (const float*)d_in[14];
    const float* gs_w2 = (const float*)d_in[15];
    const float* gs_b2 = (const float*)d_in[16];
    const float* dp_w1 = (const float*)d_in[17];
    const float* dp_b1 = (const float*)d_in[18];
    const float* dp_w2 = (const float*)d_in[19];
    const float* dp_b2 = (const float*)d_in[20];
    const float* ctx_w1 = (const float*)d_in[21];
    const float* ctx_b1 = (const float*)d_in[22];
    const float* ctx_w2 = (const float*)d_in[23];
    const float* ctx_b2 = (const float*)d_in[24];
    const float* sc_w1 = (const float*)d_in[25];
    const float* sc_b1 = (const float*)d_in[26];
    const float* sc_w2 = (const float*)d_in[27];
    const float* sc_b2 = (const float*)d_in[28];

    int B = in_sizes[0] / HS;

    precompute_kernel<<<77, 256, 0, stream>>>(card_emb, aci, ctx_w2, ctx_b2, sc_w1, sc_b1,
                                              in_w, in_b, ctx_w1, dp_w1);
    policy_kernel<<<B / 64, 256, 0, stream>>>(
        hand_cards, game_state, discard, enemy_card, hand_size, num_valid,
        enemy_emb, out_w, out_b, gs_w1, gs_b1, gs_w2, gs_b2, dp_w2, dp_b1, dp_b2,
        ctx_b1, sc_w2, sc_b2, (float*)d_out);
}

// Round 6
// 54.221 us; speedup vs baseline: 3.9188x; 1.0147x over previous
//
#include <hip/hip_runtime.h>
#include <math.h>

#define HS 8
#define E 12
#define NA 20
#define KC 4

typedef float f32x4 __attribute__((ext_vector_type(4)));
typedef short short8 __attribute__((ext_vector_type(8)));

// Precomputed, batch-independent tables:
__device__ float g_QKVT[54 * 48];                  // per-card qkv table
__device__ float g_abias[NA * 32];                 // per-action folded score bias
__device__ __align__(16) short g_dpB[2 * 4 * 64 * 16];   // dp_w1 B-frags
__device__ __align__(16) short g_ctxB[2 * 8 * 64 * 16];  // ctx_w1 B-frags
__device__ __align__(16) short g_WtB[4 * 2 * 64 * 16];   // folded Wt B-frags
// Inter-kernel feature scratch: [B][40] (feats 0..35, 36..39 zero), +64 pad for
// benign overread of the A-fragment tail (zero-weighted in MFMA).
__device__ __align__(16) float g_c36[65536 * 40 + 64];

__device__ __forceinline__ void split_bf16(float f, short& hi, short& lo) {
    unsigned u = __float_as_uint(f);
    unsigned r = (u + 0x7FFFu + ((u >> 16) & 1u)) >> 16;  // RNE to bf16
    hi = (short)r;
    float fh = __uint_as_float(r << 16);
    unsigned v = __float_as_uint(f - fh);
    unsigned r2 = (v + 0x7FFFu + ((v >> 16) & 1u)) >> 16;
    lo = (short)r2;
}

__global__ void precompute_kernel(const float* __restrict__ card_emb,
                                  const int* __restrict__ aci,
                                  const float* __restrict__ ctx_w2,
                                  const float* __restrict__ ctx_b2,
                                  const float* __restrict__ sc_w1,
                                  const float* __restrict__ sc_b1,
                                  const float* __restrict__ in_w,
                                  const float* __restrict__ in_b,
                                  const float* __restrict__ ctx_w1,
                                  const float* __restrict__ dp_w1) {
    int t = blockIdx.x * 256 + threadIdx.x;
    if (t < 640) {
        int a = t >> 5, j = t & 31;
        float arep[E];
#pragma unroll
        for (int k2 = 0; k2 < E; ++k2) arep[k2] = 0.f;
        float cnt = 0.f;
#pragma unroll
        for (int c = 0; c < KC; ++c) {
            int idx = aci[a * KC + c];
            if (idx != 0) {
                cnt += 1.f;
#pragma unroll
                for (int k2 = 0; k2 < E; ++k2) arep[k2] += card_emb[idx * E + k2];
            }
        }
        float inv = 1.f / fmaxf(cnt, 1.f);
        float s = sc_b1[j];
#pragma unroll
        for (int k2 = 0; k2 < E; ++k2) s += sc_w1[j * 140 + 128 + k2] * (arep[k2] * inv);
        for (int i = 0; i < 128; ++i) s += sc_w1[j * 140 + i] * ctx_b2[i];
        g_abias[t] = s;
    } else if (t < 3232) {
        int t2 = t - 640;
        int c = t2 / 48, col = t2 % 48;
        int h = col / 12, s = col % 12;
        float val = 0.f;
        if (s < 9) {
            int r;
            if (s < 3) r = h * 3 + s;
            else if (s < 6) r = 12 + h * 3 + (s - 3);
            else r = 24 + h * 3 + (s - 6);
            val = in_b[r];
#pragma unroll
            for (int j = 0; j < 12; ++j) val += in_w[r * 12 + j] * card_emb[c * 12 + j];
        }
        g_QKVT[t2] = val;
    } else if (t < 7328) {
        int id = t - 3232;
        int st = id >> 9, lane = (id >> 3) & 63, j = id & 7;
        int s = st >> 2, tt = st & 3;
        int g = lane >> 4, n = lane & 15;
        int k = 32 * s + 8 * g + j, col = 16 * tt + n;
        float w = (k < 54) ? dp_w1[col * 54 + k] : 0.f;
        short hi, lo;
        split_bf16(w, hi, lo);
        int base = ((st << 6) + lane) << 4;
        g_dpB[base + j] = hi;
        g_dpB[base + 8 + j] = lo;
    } else if (t < 15520) {
        int id = t - 7328;
        int st = id >> 9, lane = (id >> 3) & 63, j = id & 7;
        int s = st >> 3, tt = st & 7;
        int g = lane >> 4, n = lane & 15;
        int k = 32 * s + 8 * g + j, col = 16 * tt + n;
        float w = (k < 36) ? ctx_w1[col * 36 + k] : 0.f;
        short hi, lo;
        split_bf16(w, hi, lo);
        int base = ((st << 6) + lane) << 4;
        g_ctxB[base + j] = hi;
        g_ctxB[base + 8 + j] = lo;
    } else if (t < 19616) {
        int id = t - 15520;
        int st = id >> 9, lane = (id >> 3) & 63, j = id & 7;
        int s = st >> 1, tt = st & 1;
        int g = lane >> 4, n = lane & 15;
        int k = 32 * s + 8 * g + j, col = 16 * tt + n;
        float w = 0.f;
        for (int i = 0; i < 128; ++i) w += sc_w1[col * 140 + i] * ctx_w2[i * 128 + k];
        short hi, lo;
        split_bf16(w, hi, lo);
        int base = ((st << 6) + lane) << 4;
        g_WtB[base + j] = hi;
        g_WtB[base + 8 + j] = lo;
    }
}

#define MFMA(a, b, c) __builtin_amdgcn_mfma_f32_16x16x32_bf16(a, b, c, 0, 0, 0)

// ============ Kernel A: attention + enemy + gs + dp-MFMA -> g_c36 ============
// 256 threads = 4 waves = 64 elements. Quad map for attention/gs (el=tid>>2,
// q=tid&3), 16-lane map for dp (el2=16w+n). All outputs to global; no
// __syncthreads after prologue.
__global__ __launch_bounds__(256) void featA_kernel(
    const int* __restrict__ hand_cards, const float* __restrict__ game_state,
    const float* __restrict__ discard, const int* __restrict__ enemy_card,
    const int* __restrict__ hand_size, const float* __restrict__ enemy_emb,
    const float* __restrict__ out_w, const float* __restrict__ out_b,
    const float* __restrict__ gs_w1, const float* __restrict__ gs_b1,
    const float* __restrict__ gs_w2, const float* __restrict__ gs_b2,
    const float* __restrict__ dp_w2, const float* __restrict__ dp_b1,
    const float* __restrict__ dp_b2) {
    __shared__ __align__(16) float sQKVT[54 * 48];
    __shared__ __align__(16) float sEN[54 * 12];
    __shared__ __align__(16) float sGS1[64 * 12];
    __shared__ __align__(16) float sGS2T[64 * 8];
    __shared__ __align__(16) float sDPW2T[64 * 12];
    __shared__ __align__(16) float sOW[144];
    __shared__ float sGSB1[64];
    __shared__ float sDPB1[64];

    int tid = threadIdx.x;
    for (int i = tid; i < 54 * 48; i += 256) sQKVT[i] = g_QKVT[i];
    for (int i = tid; i < 54 * 12; i += 256) sEN[i] = enemy_emb[i];
    for (int i = tid; i < 64 * 12; i += 256) {
        int r = i / 12, c = i % 12;
        sGS1[((r & 15) * 4 + (r >> 4)) * 12 + c] = gs_w1[i];
    }
    for (int i = tid; i < 64 * 8; i += 256) {
        int r = i >> 3, c = i & 7;
        sGS2T[((r & 15) * 4 + (r >> 4)) * 8 + c] = (c < 6) ? gs_w2[c * 64 + r] : 0.f;
    }
    for (int i = tid; i < 64 * 12; i += 256) {
        int f = i / 12, c = i % 12;
        sDPW2T[i] = (c < 6) ? dp_w2[c * 64 + f] : 0.f;
    }
    if (tid < 144) sOW[tid] = out_w[tid];
    if (tid >= 192 && tid < 256) sGSB1[tid - 192] = gs_b1[tid - 192];
    if (tid >= 128 && tid < 192) sDPB1[tid - 128] = dp_b1[tid - 128];
    __syncthreads();

    int lane = tid & 63;
    int w = tid >> 6;

    // ---- quad-mapped: attention + hand_ctx + enemy + gs ----
    {
        int q = tid & 3;
        int el = tid >> 2;
        int b = blockIdx.x * 64 + el;
        int base = lane & ~3;
        float* crow = g_c36 + (size_t)b * 40;

        int hc[HS];
        {
            const int4* hp = (const int4*)(hand_cards + (size_t)b * HS);
            int4 h0 = hp[0], h1 = hp[1];
            hc[0] = h0.x; hc[1] = h0.y; hc[2] = h0.z; hc[3] = h0.w;
            hc[4] = h1.x; hc[5] = h1.y; hc[6] = h1.z; hc[7] = h1.w;
        }
        int ec = enemy_card[b];

        float qk[HS][9];
#pragma unroll
        for (int p = 0; p < HS; ++p) {
            const float4* tp = (const float4*)&sQKVT[hc[p] * 48 + q * 12];
            float4 a0 = tp[0], a1 = tp[1], a2 = tp[2];
            qk[p][0] = a0.x; qk[p][1] = a0.y; qk[p][2] = a0.z;
            qk[p][3] = a0.w; qk[p][4] = a1.x; qk[p][5] = a1.y;
            qk[p][6] = a1.z; qk[p][7] = a1.w; qk[p][8] = a2.x;
        }
        const float scale = 0.5773502691896258f;
        float attv0 = 0.f, attv1 = 0.f, attv2 = 0.f;
#pragma unroll
        for (int p = 0; p < HS; ++p) {
            float s[HS];
            float mx = -3.0e38f;
#pragma unroll
            for (int k = 0; k < HS; ++k) {
                float t = (qk[p][0] * qk[k][3] + qk[p][1] * qk[k][4] + qk[p][2] * qk[k][5]) * scale;
                t = (hc[k] != 0) ? t : -1.0e9f;
                s[k] = t;
                mx = fmaxf(mx, t);
            }
            float sum = 0.f;
#pragma unroll
            for (int k = 0; k < HS; ++k) {
                float e = __expf(s[k] - mx);
                s[k] = e;
                sum += e;
            }
            float inv = 1.f / sum;
            float a0 = 0.f, a1 = 0.f, a2 = 0.f;
#pragma unroll
            for (int k = 0; k < HS; ++k) {
                a0 += s[k] * qk[k][6];
                a1 += s[k] * qk[k][7];
                a2 += s[k] * qk[k][8];
            }
            attv0 += a0 * inv; attv1 += a1 * inv; attv2 += a2 * inv;
        }
        float attw[12];
#pragma unroll
        for (int j = 0; j < 12; ++j) {
            float v = (j % 3 == 0) ? attv0 : ((j % 3 == 1) ? attv1 : attv2);
            attw[j] = __shfl(v, base + j / 3, 64);
        }
        {
            float invlen = 1.f / fmaxf((float)hand_size[b], 1.f);
#pragma unroll
            for (int t2 = 0; t2 < 3; ++t2) {
                int r = 3 * q + t2;
                float a = 8.f * out_b[r];
#pragma unroll
                for (int e = 0; e < 12; ++e) a += sOW[r * 12 + e] * attw[e];
                crow[r] = a * invlen;  // feats 0..11
            }
        }
#pragma unroll
        for (int t2 = 0; t2 < 3; ++t2)  // feats 12..23
            crow[12 + 3 * q + t2] = sEN[ec * 12 + 3 * q + t2];

        // game_state MLP -> feats 24..29
        {
            const float4* gp = (const float4*)(game_state + (size_t)b * 12);
            float4 x0 = gp[0], x1 = gp[1], x2 = gp[2];
            float acc[6] = {0.f, 0.f, 0.f, 0.f, 0.f, 0.f};
#pragma unroll 4
            for (int jj = 0; jj < 16; ++jj) {
                const float4* wr = (const float4*)&sGS1[(jj * 4 + q) * 12];
                float4 w0 = wr[0], w1 = wr[1], w2 = wr[2];
                float h = sGSB1[q * 16 + jj];
                h += w0.x * x0.x + w0.y * x0.y + w0.z * x0.z + w0.w * x0.w;
                h += w1.x * x1.x + w1.y * x1.y + w1.z * x1.z + w1.w * x1.w;
                h += w2.x * x2.x + w2.y * x2.y + w2.z * x2.z + w2.w * x2.w;
                h = fmaxf(h, 0.f);
                const float4* w2r = (const float4*)&sGS2T[(jj * 4 + q) * 8];
                float4 wa = w2r[0], wb = w2r[1];
                acc[0] += h * wa.x; acc[1] += h * wa.y; acc[2] += h * wa.z;
                acc[3] += h * wa.w; acc[4] += h * wb.x; acc[5] += h * wb.y;
            }
#pragma unroll
            for (int c = 0; c < 6; ++c) {
                float v = acc[c];
                v += __shfl_xor(v, 1, 64);
                v += __shfl_xor(v, 2, 64);
                acc[c] = v + gs_b2[c];
            }
            if (q < 3) {
                crow[24 + 2 * q + 0] = acc[2 * q + 0];
                crow[24 + 2 * q + 1] = acc[2 * q + 1];
            }
        }
    }

    // ---- 16-lane-mapped: dp MLP via MFMA -> feats 30..35, zero 36..39 ----
    {
        int n = lane & 15, g = lane >> 4;
        int el2 = (w << 4) + n;
        int b2 = blockIdx.x * 64 + el2;
        const float* drow = discard + (size_t)b2 * 54;
        float xa[16];
        {
            const float2* p = (const float2*)(drow + 8 * g);
            float2 v0 = p[0], v1 = p[1], v2 = p[2], v3 = p[3];
            xa[0] = v0.x; xa[1] = v0.y; xa[2] = v1.x; xa[3] = v1.y;
            xa[4] = v2.x; xa[5] = v2.y; xa[6] = v3.x; xa[7] = v3.y;
        }
#pragma unroll
        for (int j = 0; j < 8; ++j) {
            int k = 32 + 8 * g + j;
            xa[8 + j] = (k < 54) ? drow[k] : 0.f;
        }
        short8 ahi0, alo0, ahi1, alo1;
#pragma unroll
        for (int j = 0; j < 8; ++j) {
            short h, l;
            split_bf16(xa[j], h, l);     ahi0[j] = h; alo0[j] = l;
            split_bf16(xa[8 + j], h, l); ahi1[j] = h; alo1[j] = l;
        }
        f32x4 dacc[4];
#pragma unroll
        for (int t = 0; t < 4; ++t) {
            float bv = sDPB1[16 * t + n];
            f32x4 cc = {bv, bv, bv, bv};
            dacc[t] = cc;
        }
#pragma unroll
        for (int t = 0; t < 4; ++t) {
#pragma unroll
            for (int s = 0; s < 2; ++s) {
                const short8* bp = (const short8*)&g_dpB[(((s * 4 + t) << 6) + lane) << 4];
                short8 bh = bp[0], bl = bp[1];
                short8 ah = s ? ahi1 : ahi0;
                short8 al = s ? alo1 : alo0;
                dacc[t] = MFMA(ah, bh, dacc[t]);
                dacc[t] = MFMA(ah, bl, dacc[t]);
                dacc[t] = MFMA(al, bh, dacc[t]);
            }
        }
        float part[4][6];
#pragma unroll
        for (int r = 0; r < 4; ++r)
#pragma unroll
            for (int c = 0; c < 6; ++c) part[r][c] = 0.f;
#pragma unroll
        for (int t = 0; t < 4; ++t) {
            const float* wrow = &sDPW2T[(16 * t + n) * 12];
            float4 wa = *(const float4*)wrow;
            float2 wb = *(const float2*)(wrow + 4);
#pragma unroll
            for (int r = 0; r < 4; ++r) {
                float h = fmaxf(dacc[t][r], 0.f);
                part[r][0] += h * wa.x; part[r][1] += h * wa.y; part[r][2] += h * wa.z;
                part[r][3] += h * wa.w; part[r][4] += h * wb.x; part[r][5] += h * wb.y;
            }
        }
#pragma unroll
        for (int r = 0; r < 4; ++r)
#pragma unroll
            for (int c = 0; c < 6; ++c) {
                float v = part[r][c];
                v += __shfl_xor(v, 1, 64);
                v += __shfl_xor(v, 2, 64);
                v += __shfl_xor(v, 4, 64);
                v += __shfl_xor(v, 8, 64);
                part[r][c] = v;
            }
        if (n < 10) {
            float bias = (n < 6) ? dp_b2[n] : 0.f;
#pragma unroll
            for (int r = 0; r < 4; ++r) {
                float dval = 0.f;
                dval = (n == 0) ? part[r][0] : dval;
                dval = (n == 1) ? part[r][1] : dval;
                dval = (n == 2) ? part[r][2] : dval;
                dval = (n == 3) ? part[r][3] : dval;
                dval = (n == 4) ? part[r][4] : dval;
                dval = (n == 5) ? part[r][5] : dval;
                // n in 6..9 writes 0 to pad cols 36..39
                g_c36[(size_t)(blockIdx.x * 64 + (w << 4) + (g << 2) + r) * 40 + 30 + n] =
                    dval + bias;
            }
        }
    }
}

// ============ Kernel B: ctx-MFMA + folded-Wt-MFMA + score -> out ============
__global__ __launch_bounds__(256) void scoreB_kernel(
    const int* __restrict__ num_valid, const float* __restrict__ ctx_b1,
    const float* __restrict__ sc_w2, const float* __restrict__ sc_b2,
    float* __restrict__ out) {
    __shared__ __align__(16) float sT[4 * 16 * 36];  // per-wave transpose buffer
    __shared__ __align__(16) float sAB[NA * 36];
    __shared__ __align__(16) float sW2[32];
    __shared__ float sCB1[128];

    int tid = threadIdx.x;
    for (int i = tid; i < NA * 36; i += 256) {
        int a = i / 36, c = i % 36;
        sAB[i] = (c < 32) ? g_abias[a * 32 + c] : 0.f;
    }
    if (tid >= 160 && tid < 192) sW2[tid - 160] = sc_w2[tid - 160];
    if (tid < 128) sCB1[tid] = ctx_b1[tid];
    __syncthreads();

    int lane = tid & 63;
    int w = tid >> 6;
    int n = lane & 15, g = lane >> 4;
    int el2 = (w << 4) + n;
    size_t b2 = (size_t)blockIdx.x * 64 + el2;
    float* sTT = sT + w * 576;

    f32x4 uacc[2];
    {
        f32x4 z = {0.f, 0.f, 0.f, 0.f};
        uacc[0] = z; uacc[1] = z;
    }
    {
        const float* arow = g_c36 + b2 * 40;
        float ca[16];
        {
            const float4* ap0 = (const float4*)(arow + 8 * g);
            float4 a0 = ap0[0], a1 = ap0[1];
            const float4* ap1 = (const float4*)(arow + 32 + 8 * g);  // tail overread: zero-weighted
            float4 a2 = ap1[0], a3 = ap1[1];
            ca[0] = a0.x; ca[1] = a0.y; ca[2] = a0.z; ca[3] = a0.w;
            ca[4] = a1.x; ca[5] = a1.y; ca[6] = a1.z; ca[7] = a1.w;
            ca[8] = a2.x; ca[9] = a2.y; ca[10] = a2.z; ca[11] = a2.w;
            ca[12] = a3.x; ca[13] = a3.y; ca[14] = a3.z; ca[15] = a3.w;
        }
        short8 cahi0, calo0, cahi1, calo1;
#pragma unroll
        for (int j = 0; j < 8; ++j) {
            short h, l;
            split_bf16(ca[j], h, l);     cahi0[j] = h; calo0[j] = l;
            split_bf16(ca[8 + j], h, l); cahi1[j] = h; calo1[j] = l;
        }
#pragma unroll
        for (int p = 0; p < 4; ++p) {
            f32x4 cacc[2];
#pragma unroll
            for (int t2 = 0; t2 < 2; ++t2) {
                float bv = sCB1[(p * 2 + t2) * 16 + n];
                f32x4 cc = {bv, bv, bv, bv};
                cacc[t2] = cc;
            }
#pragma unroll
            for (int t2 = 0; t2 < 2; ++t2) {
                int tt = p * 2 + t2;
#pragma unroll
                for (int s = 0; s < 2; ++s) {
                    const short8* bp = (const short8*)&g_ctxB[(((s * 8 + tt) << 6) + lane) << 4];
                    short8 bh = bp[0], bl = bp[1];
                    short8 ah = s ? cahi1 : cahi0;
                    short8 al = s ? calo1 : calo0;
                    cacc[t2] = MFMA(ah, bh, cacc[t2]);
                    cacc[t2] = MFMA(ah, bl, cacc[t2]);
                    cacc[t2] = MFMA(al, bh, cacc[t2]);
                }
            }
#pragma unroll
            for (int t2 = 0; t2 < 2; ++t2)
#pragma unroll
                for (int r = 0; r < 4; ++r)
                    sTT[((g << 2) + r) * 36 + t2 * 16 + n] = fmaxf(cacc[t2][r], 0.f);
            asm volatile("s_waitcnt lgkmcnt(0)" ::: "memory");
            float ha[8];
            {
                const float4* hp = (const float4*)&sTT[n * 36 + 8 * g];
                float4 h0 = hp[0], h1 = hp[1];
                ha[0] = h0.x; ha[1] = h0.y; ha[2] = h0.z; ha[3] = h0.w;
                ha[4] = h1.x; ha[5] = h1.y; ha[6] = h1.z; ha[7] = h1.w;
            }
            short8 whi, wlo;
#pragma unroll
            for (int j = 0; j < 8; ++j) {
                short h, l;
                split_bf16(ha[j], h, l);
                whi[j] = h; wlo[j] = l;
            }
#pragma unroll
            for (int t2 = 0; t2 < 2; ++t2) {
                const short8* bp = (const short8*)&g_WtB[(((p * 2 + t2) << 6) + lane) << 4];
                short8 bh = bp[0], bl = bp[1];
                uacc[t2] = MFMA(whi, bh, uacc[t2]);
                uacc[t2] = MFMA(whi, bl, uacc[t2]);
                uacc[t2] = MFMA(wlo, bh, uacc[t2]);
            }
            asm volatile("s_waitcnt lgkmcnt(0)" ::: "memory");
        }
    }

    // score layer
    {
#pragma unroll
        for (int t2 = 0; t2 < 2; ++t2)
#pragma unroll
            for (int r = 0; r < 4; ++r)
                sTT[((g << 2) + r) * 36 + t2 * 16 + n] = uacc[t2][r];
        asm volatile("s_waitcnt lgkmcnt(0)" ::: "memory");
        float uu[32];
        {
            const float4* up = (const float4*)&sTT[n * 36];
#pragma unroll
            for (int j8 = 0; j8 < 8; ++j8) {
                float4 v = up[j8];
                uu[4 * j8 + 0] = v.x; uu[4 * j8 + 1] = v.y;
                uu[4 * j8 + 2] = v.z; uu[4 * j8 + 3] = v.w;
            }
        }
        float w2v[32];
        {
            const float4* wp = (const float4*)sW2;
#pragma unroll
            for (int j8 = 0; j8 < 8; ++j8) {
                float4 v = wp[j8];
                w2v[4 * j8 + 0] = v.x; w2v[4 * j8 + 1] = v.y;
                w2v[4 * j8 + 2] = v.z; w2v[4 * j8 + 3] = v.w;
            }
        }
        int nva = num_valid[0];
        float sb2 = sc_b2[0];
#pragma unroll
        for (int t = 0; t < 5; ++t) {
            int a = g * 5 + t;
            const float4* ab = (const float4*)&sAB[a * 36];
            float s = sb2;
#pragma unroll
            for (int j8 = 0; j8 < 8; ++j8) {
                float4 av = ab[j8];
                s += w2v[4 * j8 + 0] * fmaxf(uu[4 * j8 + 0] + av.x, 0.f);
                s += w2v[4 * j8 + 1] * fmaxf(uu[4 * j8 + 1] + av.y, 0.f);
                s += w2v[4 * j8 + 2] * fmaxf(uu[4 * j8 + 2] + av.z, 0.f);
                s += w2v[4 * j8 + 3] * fmaxf(uu[4 * j8 + 3] + av.w, 0.f);
            }
            out[b2 * NA + a] = (a < nva) ? s : -1.0e8f;
        }
    }
}

extern "C" void kernel_launch(void* const* d_in, const int* in_sizes, int n_in,
                              void* d_out, int out_size, void* d_ws, size_t ws_size,
                              hipStream_t stream) {
    const int* hand_cards = (const int*)d_in[0];
    const float* game_state = (const float*)d_in[1];
    const float* discard = (const float*)d_in[2];
    const int* enemy_card = (const int*)d_in[3];
    const int* hand_size = (const int*)d_in[4];
    const int* aci = (const int*)d_in[5];
    const int* num_valid = (const int*)d_in[6];
    const float* card_emb = (const float*)d_in[7];
    const float* enemy_emb = (const float*)d_in[8];
    const float* in_w = (const float*)d_in[9];
    const float* in_b = (const float*)d_in[10];
    const float* out_w = (const float*)d_in[11];
    const float* out_b = (const float*)d_in[12];
    const float* gs_w1 = (const float*)d_in[13];
    const float* gs_b1 = (const float*)d_in[14];
    const float* gs_w2 = (const float*)d_in[15];
    const float* gs_b2 = (const float*)d_in[16];
    const float* dp_w1 = (const float*)d_in[17];
    const float* dp_b1 = (const float*)d_in[18];
    const float* dp_w2 = (const float*)d_in[19];
    const float* dp_b2 = (const float*)d_in[20];
    const float* ctx_w1 = (const float*)d_in[21];
    const float* ctx_b1 = (const float*)d_in[22];
    const float* ctx_w2 = (const float*)d_in[23];
    const float* ctx_b2 = (const float*)d_in[24];
    const float* sc_w1 = (const float*)d_in[25];
    const float* sc_b1 = (const float*)d_in[26];
    const float* sc_w2 = (const float*)d_in[27];
    const float* sc_b2 = (const float*)d_in[28];

    int B = in_sizes[0] / HS;

    precompute_kernel<<<77, 256, 0, stream>>>(card_emb, aci, ctx_w2, ctx_b2, sc_w1, sc_b1,
                                              in_w, in_b, ctx_w1, dp_w1);
    featA_kernel<<<B / 64, 256, 0, stream>>>(
        hand_cards, game_state, discard, enemy_card, hand_size, enemy_emb,
        out_w, out_b, gs_w1, gs_b1, gs_w2, gs_b2, dp_w2, dp_b1, dp_b2);
    scoreB_kernel<<<B / 64, 256, 0, stream>>>(num_valid, ctx_b1, sc_w2, sc_b2,
                                              (float*)d_out);
}